// Round 7
// baseline (320.064 us; speedup 1.0000x reference)
//
#include <hip/hip_runtime.h>
#include <cstdint>
#include <cstddef>

#define B_   4
#define C_   512
#define N_   4096
#define BN_EPS 1e-5f

typedef __attribute__((ext_vector_type(8))) short short8;
typedef __attribute__((ext_vector_type(8))) unsigned short ushort8;
typedef __attribute__((ext_vector_type(4))) unsigned short us4_t;
typedef __attribute__((ext_vector_type(4))) float f32x4;

__device__ __forceinline__ unsigned short f2b(float f) {
  union { float f; unsigned u; } v; v.f = f;
  unsigned u = v.u;
  return (unsigned short)((u + 0x7fffu + ((u >> 16) & 1u)) >> 16);
}
__device__ __forceinline__ float b2f(unsigned short h) {
  union { unsigned u; float f; } v; v.u = ((unsigned)h) << 16;
  return v.f;
}
__device__ __forceinline__ void async16(const void* g, void* l) {
  __builtin_amdgcn_global_load_lds((const __attribute__((address_space(1))) void*)g,
                                   (__attribute__((address_space(3))) void*)l, 16, 0, 0);
}

// ---------------- conversion kernels ----------------

__global__ __launch_bounds__(256) void convert_x_k(const float* __restrict__ x,
                                                   unsigned short* __restrict__ xcn,
                                                   unsigned short* __restrict__ xnc) {
  __shared__ float tile[64][65];
  int c0 = blockIdx.x * 64, n0 = blockIdx.y * 64, b = blockIdx.z;
  const float* xb = x + ((size_t)b * C_ + c0) * N_ + n0;
  unsigned short* cn = xcn + ((size_t)b * C_ + c0) * N_ + n0;
#pragma unroll
  for (int j = 0; j < 16; ++j) {
    int lin = j * 256 + threadIdx.x;
    int rr = lin >> 6, cc = lin & 63;
    float v = xb[(size_t)rr * N_ + cc];
    cn[(size_t)rr * N_ + cc] = f2b(v);
    tile[cc][rr] = v;
  }
  __syncthreads();
  unsigned short* nc = xnc + ((size_t)b * N_ + n0) * C_ + c0;
#pragma unroll
  for (int j = 0; j < 16; ++j) {
    int lin = j * 256 + threadIdx.x;
    int rr = lin >> 6, cc = lin & 63;
    nc[(size_t)rr * C_ + cc] = f2b(tile[rr][cc]);
  }
}

__global__ __launch_bounds__(256) void convert_w_k(const float* __restrict__ wq, const float* __restrict__ wk,
                                                   const float* __restrict__ wv, const float* __restrict__ wf,
                                                   unsigned short* __restrict__ wqk,
                                                   unsigned short* __restrict__ wvb,
                                                   unsigned short* __restrict__ wfb) {
  int i = blockIdx.x * 256 + threadIdx.x;
  if (i < 128 * 512) {
    int row = i >> 9, col = i & 511;
    float v = (row < 64) ? wq[row * 512 + col] : wk[(row - 64) * 512 + col];
    wqk[i] = f2b(v);
  }
  wvb[i] = f2b(wv[i]);
  wfb[i] = f2b(wf[i]);
}

// ---------------- generic MFMA GEMM:  C[m,n] = sum_k A[m,k] * B'[n,k] ----------------

enum { EPI_BF16 = 0, EPI_F32 = 1 };

template<int EPI, bool SPLITK = false>
__global__ __launch_bounds__(256)
void gemm_bt(const unsigned short* __restrict__ A, size_t lda, size_t sA,
             const unsigned short* __restrict__ Bm, size_t ldb, size_t sB,
             void* __restrict__ Cv, size_t ldc, size_t sCbytes, int K) {
  const int bz = blockIdx.z;
  const int m0 = blockIdx.x * 128, n0 = blockIdx.y * 128;
  char* Cb;
  if (SPLITK) {
    int bidx = bz & 3, ch = bz >> 2;
    A  += (size_t)bidx * sA + (size_t)ch * (size_t)K;
    Bm += (size_t)bidx * sB + (size_t)ch * (size_t)K;
    Cb = (char*)Cv + (size_t)bidx * sCbytes + (size_t)ch * 4u * sCbytes;
  } else {
    A  += (size_t)bz * sA;
    Bm += (size_t)bz * sB;
    Cb = (char*)Cv + (size_t)bz * sCbytes;
  }
  __shared__ unsigned short lsA[128 * 32];
  __shared__ unsigned short lsB[128 * 32];
  const int tid = threadIdx.x, lane = tid & 63, w = tid >> 6;
  const int wm = (w >> 1) * 64, wn = (w & 1) * 64;
  const int fr = lane & 15, fk = (lane >> 4) * 8;
  f32x4 acc[4][4];
#pragma unroll
  for (int i = 0; i < 4; ++i)
#pragma unroll
    for (int j = 0; j < 4; ++j) acc[i][j] = (f32x4){0.f, 0.f, 0.f, 0.f};

  const int i0 = tid, i1 = tid + 256;
  for (int k0 = 0; k0 < K; k0 += 32) {
    async16(A  + (size_t)(m0 + (i0 >> 2)) * lda + k0 + (i0 & 3) * 8, (char*)lsA + i0 * 16);
    async16(A  + (size_t)(m0 + (i1 >> 2)) * lda + k0 + (i1 & 3) * 8, (char*)lsA + i1 * 16);
    async16(Bm + (size_t)(n0 + (i0 >> 2)) * ldb + k0 + (i0 & 3) * 8, (char*)lsB + i0 * 16);
    async16(Bm + (size_t)(n0 + (i1 >> 2)) * ldb + k0 + (i1 & 3) * 8, (char*)lsB + i1 * 16);
    __syncthreads();
    short8 af[4], bfr[4];
#pragma unroll
    for (int mi = 0; mi < 4; ++mi)
      af[mi] = *(const short8*)&lsA[(wm + mi * 16 + fr) * 32 + fk];
#pragma unroll
    for (int ni = 0; ni < 4; ++ni)
      bfr[ni] = *(const short8*)&lsB[(wn + ni * 16 + fr) * 32 + fk];
#pragma unroll
    for (int mi = 0; mi < 4; ++mi)
#pragma unroll
      for (int ni = 0; ni < 4; ++ni)
        acc[mi][ni] = __builtin_amdgcn_mfma_f32_16x16x32_bf16(af[mi], bfr[ni], acc[mi][ni], 0, 0, 0);
    __syncthreads();
  }
#pragma unroll
  for (int mi = 0; mi < 4; ++mi)
#pragma unroll
    for (int ni = 0; ni < 4; ++ni)
#pragma unroll
      for (int r = 0; r < 4; ++r) {
        int gr = m0 + wm + mi * 16 + (lane >> 4) * 4 + r;
        int gc = n0 + wn + ni * 16 + fr;
        float v = acc[mi][ni][r];
        if (EPI == EPI_BF16) ((unsigned short*)Cb)[(size_t)gr * ldc + gc] = f2b(v);
        else                 ((float*)Cb)[(size_t)gr * ldc + gc] = v;
      }
}

// ---------------- fused position attention (v4) ----------------
// per block: 128 Q-rows x 256 out-cols; K-tiles of 128 over m (32 iters).
// Q and K fragments in REGISTERS (K dbuf-prefetched during PV).
// E-phase reads NO LDS: mfma(Kreg,Qreg) -> __expf -> P write (swizzled LDS).
// V staged via global_load_lds issued post-PV, drained at post-E barrier
// (E compute covers the load; LDS pipe idle during E).
// epilogue: sT = bf16(gpa*acc/l + gca*caT + 2x)
#define QR 128
#define CC 256
#define KT 128
#define NIT (N_ / KT)

__global__ __launch_bounds__(512, 2)
void fused_pa_k(const unsigned short* __restrict__ qkT,   // [B][N][128] (q|k)
                const unsigned short* __restrict__ vmat,  // [B][C][N]
                const unsigned short* __restrict__ caT,   // [B][N][C]
                const unsigned short* __restrict__ xnc,   // [B][N][C]
                const float* __restrict__ gpa_p, const float* __restrict__ gca_p,
                unsigned short* __restrict__ sT) {        // [B][N][C]
  __shared__ unsigned short lsV[CC * KT];     // 64KB, row=256B, 16 granules
  __shared__ unsigned short lsP[QR * KT];     // 32KB, row=256B, 16 granules
  __shared__ float lsL[8][QR];
  __shared__ float invL[QR];

  const int bid = blockIdx.x;
  const int combo = bid & 7;                 // b*2+chalf -> same XCD shares V-half
  const int b = combo >> 1, chalf = combo & 1;
  const int qt = bid >> 3;
  const int n0 = qt * QR, c0 = chalf * CC;

  const int tid = threadIdx.x, lane = tid & 63, w = tid >> 6;
  const int fr = lane & 15, fq = lane >> 4;  // fragment row / k-quarter
  const int wr = w >> 2, wc = w & 3;         // PV wave out-tile 64x64
  const int ms = w * 16;                     // E-phase m-slice

  const unsigned short* qk_b = qkT + (size_t)b * N_ * 128;
  const unsigned short* v_b  = vmat + (size_t)b * C_ * N_;

  // ---- Q fragments in registers (row n0+f*16+fr, k = kk*32+fq*8) ----
  short8 bq[8][2];
#pragma unroll
  for (int f = 0; f < 8; ++f)
#pragma unroll
    for (int kk = 0; kk < 2; ++kk)
      bq[f][kk] = *(const short8*)&qk_b[(size_t)(n0 + f * 16 + fr) * 128 + kk * 32 + fq * 8];

  f32x4 acc[4][4];
#pragma unroll
  for (int i = 0; i < 4; ++i)
#pragma unroll
    for (int j = 0; j < 4; ++j) acc[i][j] = (f32x4){0.f, 0.f, 0.f, 0.f};
  float lsum[8];
#pragma unroll
  for (int f = 0; f < 8; ++f) lsum[f] = 0.f;

  auto stageV = [&](int mt) {
#pragma unroll
    for (int j = 0; j < 8; ++j) {
      int idx = j * 512 + tid;
      int c = idx >> 4, g = idx & 15;
      async16(v_b + (size_t)(c0 + c) * N_ + mt + ((g ^ (c & 7)) << 3), (char*)lsV + idx * 16);
    }
  };
  auto loadK = [&](int mt, short8& k0, short8& k1) {
    const unsigned short* kr = &qk_b[(size_t)(mt + ms + fr) * 128 + 64 + fq * 8];
    k0 = *(const short8*)kr;
    k1 = *(const short8*)(kr + 32);
  };
  // E^T = K . Q^T; wave w owns m-slice [ms, ms+16); all-register inputs.
  auto ephase = [&](short8 k0, short8 k1) {
#pragma unroll
    for (int f = 0; f < 8; ++f) {
      f32x4 e = (f32x4){0.f, 0.f, 0.f, 0.f};
      e = __builtin_amdgcn_mfma_f32_16x16x32_bf16(k0, bq[f][0], e, 0, 0, 0);
      e = __builtin_amdgcn_mfma_f32_16x16x32_bf16(k1, bq[f][1], e, 0, 0, 0);
      float p0 = __expf(e[0]), p1 = __expf(e[1]), p2 = __expf(e[2]), p3 = __expf(e[3]);
      float part = (p0 + p1) + (p2 + p3);
      part += __shfl_xor(part, 16, 64);
      part += __shfl_xor(part, 32, 64);
      lsum[f] += part;
      int n = f * 16 + fr;                     // P row
      int mb = ms + fq * 4;                    // 4 consecutive m
      us4_t pk = { f2b(p0), f2b(p1), f2b(p2), f2b(p3) };
      *(us4_t*)((char*)lsP + n * 256 + ((((mb >> 3) ^ (n & 7)) << 3) + (mb & 7)) * 2) = pk;
    }
  };
  // PV: out[n][c] += P[n][m] * V[c][m]
  auto pvphase = [&]() {
#pragma unroll
    for (int kk4 = 0; kk4 < 4; ++kk4) {
      short8 pa[4], vbf[4];
#pragma unroll
      for (int mi = 0; mi < 4; ++mi) {
        int n = wr * 64 + mi * 16 + fr;
        pa[mi] = *(const short8*)((const char*)lsP + n * 256 + (((kk4 * 4 + fq) ^ (n & 7)) << 4));
      }
#pragma unroll
      for (int ni = 0; ni < 4; ++ni) {
        int c = wc * 64 + ni * 16 + fr;
        vbf[ni] = *(const short8*)((const char*)lsV + c * 256 + (((kk4 * 4 + fq) ^ (c & 7)) << 4));
      }
#pragma unroll
      for (int mi = 0; mi < 4; ++mi)
#pragma unroll
        for (int ni = 0; ni < 4; ++ni)
          acc[mi][ni] = __builtin_amdgcn_mfma_f32_16x16x32_bf16(pa[mi], vbf[ni], acc[mi][ni], 0, 0, 0);
    }
  };

  short8 kA0, kA1, kB0, kB1;
  stageV(0);
  loadK(0, kA0, kA1);
  __syncthreads();                 // V(0) resident, kA waited on first use

  for (int t = 0; t < NIT; t += 2) {
    // ---- even iter t: compute from kA + lsV(t) ----
    ephase(kA0, kA1);              // no LDS reads; covers stageV(t) drain issued last iter
    loadK((t + 1) * KT, kB0, kB1); // prefetch K(t+1) into regs (covered by PV)
    __syncthreads();               // lsP visible; V-stage (issued at t-1 tail) drained
    pvphase();
    __syncthreads();               // lsV reads done -> safe to overwrite
    stageV((t + 1) * KT);          // streams into idle LDS pipe under next E
    // ---- odd iter t+1: compute from kB + lsV(t+1) ----
    ephase(kB0, kB1);
    if (t + 2 < NIT) loadK((t + 2) * KT, kA0, kA1);
    __syncthreads();               // lsP visible; V(t+1) drained
    pvphase();
    __syncthreads();
    if (t + 2 < NIT) stageV((t + 2) * KT);
  }

  // reduce rowsums across waves -> 1/l
  if (lane < 16) {
#pragma unroll
    for (int f = 0; f < 8; ++f) lsL[w][f * 16 + lane] = lsum[f];
  }
  __syncthreads();
  if (tid < QR) {
    float s = 0.f;
#pragma unroll
    for (int ww = 0; ww < 8; ++ww) s += lsL[ww][tid];
    invL[tid] = 1.f / s;
  }
  __syncthreads();

  const float gpa = gpa_p[0], gca = gca_p[0];
#pragma unroll
  for (int mi = 0; mi < 4; ++mi)
#pragma unroll
    for (int ni = 0; ni < 4; ++ni)
#pragma unroll
      for (int r = 0; r < 4; ++r) {
        int nl = wr * 64 + mi * 16 + fq * 4 + r;
        int gn = n0 + nl;
        int gc = c0 + wc * 64 + ni * 16 + fr;
        size_t eo = ((size_t)b * N_ + gn) * C_ + gc;
        float sv = gpa * acc[mi][ni][r] * invL[nl] + gca * b2f(caT[eo]) + 2.f * b2f(xnc[eo]);
        sT[eo] = f2b(sv);
      }
}

// ---------------- channel-attention softmax over ce partials ----------------
__global__ __launch_bounds__(256) void ce_softmax_k(const float* __restrict__ cepart,
                                                    unsigned short* __restrict__ cattn) {
  int wid = threadIdx.x >> 6, lane = threadIdx.x & 63;
  size_t row = (size_t)blockIdx.x * 4 + wid;
  float v[8]; float mn = 3.4e38f;
#pragma unroll
  for (int i = 0; i < 8; ++i) {
    size_t idx = row * C_ + (size_t)(i * 64 + lane);
    float t = cepart[idx] + cepart[idx + 1048576] + cepart[idx + 2097152] + cepart[idx + 3145728];
    v[i] = t; mn = fminf(mn, t);
  }
#pragma unroll
  for (int o = 1; o < 64; o <<= 1) mn = fminf(mn, __shfl_xor(mn, o, 64));
  float s = 0.f, p[8];
#pragma unroll
  for (int i = 0; i < 8; ++i) { p[i] = expf(mn - v[i]); s += p[i]; }
#pragma unroll
  for (int o = 1; o < 64; o <<= 1) s += __shfl_xor(s, o, 64);
  float inv = 1.f / s;
  unsigned short* orow = cattn + row * C_;
#pragma unroll
  for (int i = 0; i < 8; ++i) orow[i * 64 + lane] = f2b(p[i] * inv);
}

// ---------------- BN statistics (two stage, deterministic) ----------------
__global__ __launch_bounds__(256) void bn_part_k(const float* __restrict__ yT,
                                                 float* __restrict__ part) {
  int p = blockIdx.x, t = threadIdx.x;
  const float* base = yT + (size_t)p * 256 * C_;
  float s0 = 0, q0 = 0, s1 = 0, q1 = 0;
  for (int r = 0; r < 256; ++r) {
    float a = base[(size_t)r * C_ + t];
    float b = base[(size_t)r * C_ + t + 256];
    s0 += a; q0 += a * a; s1 += b; q1 += b * b;
  }
  float* pp = part + (size_t)p * 1024;
  pp[t] = s0; pp[t + 256] = s1; pp[t + 512] = q0; pp[t + 768] = q1;
}

__global__ __launch_bounds__(256) void bn_final_k(const float* __restrict__ part,
                                                  const float* __restrict__ bns,
                                                  const float* __restrict__ bnb,
                                                  float* __restrict__ ab) {
  int t = threadIdx.x;
#pragma unroll
  for (int cc = 0; cc < 2; ++cc) {
    int c = t + cc * 256;
    float s = 0, q = 0;
    for (int p = 0; p < 64; ++p) { s += part[p * 1024 + c]; q += part[p * 1024 + 512 + c]; }
    float mean = s * (1.f / 16384.f);
    float var  = q * (1.f / 16384.f) - mean * mean;
    float istd = rsqrtf(var + BN_EPS);
    float a = bns[c] * istd;
    float b = bnb[c] - mean * a;
    ab[c * 2] = a; ab[c * 2 + 1] = b;
  }
}

__global__ __launch_bounds__(256) void bn_apply_k(const float* __restrict__ yT,
                                                  const float* __restrict__ ab,
                                                  float* __restrict__ out) {
  __shared__ float tile[64][65];
  int n0 = blockIdx.x * 64, o0 = blockIdx.y * 64, b = blockIdx.z;
  const float* yb = yT + ((size_t)b * N_ + n0) * C_ + o0;
#pragma unroll
  for (int j = 0; j < 16; ++j) {
    int lin = j * 256 + threadIdx.x;
    int rr = lin >> 6, cc = lin & 63;
    float v = yb[(size_t)rr * C_ + cc];
    float a = ab[(o0 + cc) * 2], bb = ab[(o0 + cc) * 2 + 1];
    tile[cc][rr] = fmaxf(v * a + bb, 0.f);
  }
  __syncthreads();
  float* ob = out + ((size_t)b * C_ + o0) * N_ + n0;
#pragma unroll
  for (int j = 0; j < 16; ++j) {
    int lin = j * 256 + threadIdx.x;
    int rr = lin >> 6, cc = lin & 63;
    ob[(size_t)rr * N_ + cc] = tile[rr][cc];
  }
}

// ---------------- host launch ----------------

extern "C" void kernel_launch(void* const* d_in, const int* in_sizes, int n_in,
                              void* d_out, int out_size, void* d_ws, size_t ws_size,
                              hipStream_t stream) {
  (void)in_sizes; (void)n_in; (void)out_size; (void)ws_size;
  const float* x   = (const float*)d_in[0];
  const float* wq  = (const float*)d_in[1];
  const float* wk  = (const float*)d_in[2];
  const float* wv  = (const float*)d_in[3];
  const float* wf  = (const float*)d_in[4];
  const float* gpa = (const float*)d_in[5];
  const float* gca = (const float*)d_in[6];
  const float* bns = (const float*)d_in[7];
  const float* bnb = (const float*)d_in[8];
  float* out = (float*)d_out;

  char* ws = (char*)d_ws;
  size_t off = 0;
  auto carve = [&](size_t bytes) -> char* {
    off = (off + 255) & ~(size_t)255;
    char* p = ws + off; off += bytes; return p;
  };

  unsigned short* xcn   = (unsigned short*)carve((size_t)B_ * C_ * N_ * 2);  // reused as sT
  unsigned short* xnc   = (unsigned short*)carve((size_t)B_ * C_ * N_ * 2);
  unsigned short* wqkb  = (unsigned short*)carve(128 * 512 * 2);
  unsigned short* wvb   = (unsigned short*)carve(512 * 512 * 2);
  unsigned short* wfb   = (unsigned short*)carve(512 * 512 * 2);
  unsigned short* qkT   = (unsigned short*)carve((size_t)B_ * N_ * 128 * 2);
  unsigned short* vmat  = (unsigned short*)carve((size_t)B_ * C_ * N_ * 2);
  float*          cepart= (float*)carve((size_t)4 * B_ * 512 * 512 * 4);     // reused as yT
  unsigned short* cattn = (unsigned short*)carve((size_t)B_ * 512 * 512 * 2);
  unsigned short* caT   = (unsigned short*)carve((size_t)B_ * N_ * C_ * 2);
  float*          bnpart= (float*)carve((size_t)64 * 1024 * 4);
  float*          abv   = (float*)carve(512 * 2 * 4);

  float* yT = cepart;                 // overlay: cepart dead after ce_softmax
  unsigned short* sT = xcn;           // overlay: xcn dead after ce GEMM

  // 1) conversions
  convert_x_k<<<dim3(C_ / 64, N_ / 64, B_), 256, 0, stream>>>(x, xcn, xnc);
  convert_w_k<<<dim3(1024), 256, 0, stream>>>(wq, wk, wv, wf, wqkb, wvb, wfb);

  // 2) qkT[n][0:128] = xnc @ wqk^T
  gemm_bt<EPI_BF16><<<dim3(32, 1, 4), 256, 0, stream>>>(
      xnc, 512, (size_t)N_ * C_, wqkb, 512, 0,
      qkT, 128, (size_t)N_ * 128 * 2, 512);

  // 3) v[c][m] = wv @ x
  gemm_bt<EPI_BF16><<<dim3(4, 32, 4), 256, 0, stream>>>(
      wvb, 512, 0, xnc, 512, (size_t)N_ * C_,
      vmat, N_, (size_t)C_ * N_ * 2, 512);

  // 4) ce partials = X X^T (split-K x4)
  gemm_bt<EPI_F32, true><<<dim3(4, 4, 16), 256, 0, stream>>>(
      xcn, N_, (size_t)C_ * N_, xcn, N_, (size_t)C_ * N_,
      cepart, 512, (size_t)512 * 512 * 4, 1024);

  // 5) channel softmax -> cattn bf16
  ce_softmax_k<<<dim3(B_ * 512 / 4), 256, 0, stream>>>(cepart, cattn);

  // 6) caT[n][c] = xnc @ cattn^T
  gemm_bt<EPI_BF16><<<dim3(32, 4, 4), 256, 0, stream>>>(
      xnc, 512, (size_t)N_ * C_, cattn, 512, (size_t)512 * 512,
      caT, 512, (size_t)N_ * C_ * 2, 512);

  // 7) fused position attention + combine epilogue -> sT
  fused_pa_k<<<dim3(256), 512, 0, stream>>>(qkT, vmat, caT, xnc, gpa, gca, sT);

  // 8) yT[n][o] = sT @ wfuse^T (fp32)
  gemm_bt<EPI_F32><<<dim3(32, 4, 4), 256, 0, stream>>>(
      sT, 512, (size_t)N_ * C_, wfb, 512, 0,
      yT, 512, (size_t)N_ * C_ * 4, 512);

  // 9) BN stats + apply + transpose + relu
  bn_part_k<<<dim3(64), 256, 0, stream>>>(yT, bnpart);
  bn_final_k<<<dim3(1), 256, 0, stream>>>(bnpart, bns, bnb, abv);
  bn_apply_k<<<dim3(N_ / 64, C_ / 64, B_), 256, 0, stream>>>(yT, abv, out);
}

// Round 8
// 319.927 us; speedup vs baseline: 1.0004x; 1.0004x over previous
//
#include <hip/hip_runtime.h>
#include <cstdint>
#include <cstddef>

#define B_   4
#define C_   512
#define N_   4096
#define BN_EPS 1e-5f

typedef __attribute__((ext_vector_type(8))) short short8;
typedef __attribute__((ext_vector_type(8))) unsigned short ushort8;
typedef __attribute__((ext_vector_type(4))) unsigned short us4_t;
typedef __attribute__((ext_vector_type(4))) float f32x4;

__device__ __forceinline__ unsigned short f2b(float f) {
  union { float f; unsigned u; } v; v.f = f;
  unsigned u = v.u;
  return (unsigned short)((u + 0x7fffu + ((u >> 16) & 1u)) >> 16);
}
__device__ __forceinline__ float b2f(unsigned short h) {
  union { unsigned u; float f; } v; v.u = ((unsigned)h) << 16;
  return v.f;
}
__device__ __forceinline__ void async16(const void* g, void* l) {
  __builtin_amdgcn_global_load_lds((const __attribute__((address_space(1))) void*)g,
                                   (__attribute__((address_space(3))) void*)l, 16, 0, 0);
}

// ---------------- conversion kernels ----------------

__global__ __launch_bounds__(256) void convert_x_k(const float* __restrict__ x,
                                                   unsigned short* __restrict__ xcn,
                                                   unsigned short* __restrict__ xnc) {
  __shared__ float tile[64][65];
  int c0 = blockIdx.x * 64, n0 = blockIdx.y * 64, b = blockIdx.z;
  const float* xb = x + ((size_t)b * C_ + c0) * N_ + n0;
  unsigned short* cn = xcn + ((size_t)b * C_ + c0) * N_ + n0;
#pragma unroll
  for (int j = 0; j < 16; ++j) {
    int lin = j * 256 + threadIdx.x;
    int rr = lin >> 6, cc = lin & 63;
    float v = xb[(size_t)rr * N_ + cc];
    cn[(size_t)rr * N_ + cc] = f2b(v);
    tile[cc][rr] = v;
  }
  __syncthreads();
  unsigned short* nc = xnc + ((size_t)b * N_ + n0) * C_ + c0;
#pragma unroll
  for (int j = 0; j < 16; ++j) {
    int lin = j * 256 + threadIdx.x;
    int rr = lin >> 6, cc = lin & 63;
    nc[(size_t)rr * C_ + cc] = f2b(tile[rr][cc]);
  }
}

__global__ __launch_bounds__(256) void convert_w_k(const float* __restrict__ wq, const float* __restrict__ wk,
                                                   const float* __restrict__ wv, const float* __restrict__ wf,
                                                   unsigned short* __restrict__ wqk,
                                                   unsigned short* __restrict__ wvb,
                                                   unsigned short* __restrict__ wfb) {
  int i = blockIdx.x * 256 + threadIdx.x;
  if (i < 128 * 512) {
    int row = i >> 9, col = i & 511;
    float v = (row < 64) ? wq[row * 512 + col] : wk[(row - 64) * 512 + col];
    wqk[i] = f2b(v);
  }
  wvb[i] = f2b(wv[i]);
  wfb[i] = f2b(wf[i]);
}

// ---------------- generic MFMA GEMM:  C[m,n] = sum_k A[m,k] * B'[n,k] ----------------

enum { EPI_BF16 = 0, EPI_F32 = 1 };

template<int EPI, bool SPLITK = false>
__global__ __launch_bounds__(256)
void gemm_bt(const unsigned short* __restrict__ A, size_t lda, size_t sA,
             const unsigned short* __restrict__ Bm, size_t ldb, size_t sB,
             void* __restrict__ Cv, size_t ldc, size_t sCbytes, int K) {
  const int bz = blockIdx.z;
  const int m0 = blockIdx.x * 128, n0 = blockIdx.y * 128;
  char* Cb;
  if (SPLITK) {
    int bidx = bz & 3, ch = bz >> 2;
    A  += (size_t)bidx * sA + (size_t)ch * (size_t)K;
    Bm += (size_t)bidx * sB + (size_t)ch * (size_t)K;
    Cb = (char*)Cv + (size_t)bidx * sCbytes + (size_t)ch * 4u * sCbytes;
  } else {
    A  += (size_t)bz * sA;
    Bm += (size_t)bz * sB;
    Cb = (char*)Cv + (size_t)bz * sCbytes;
  }
  __shared__ unsigned short lsA[128 * 32];
  __shared__ unsigned short lsB[128 * 32];
  const int tid = threadIdx.x, lane = tid & 63, w = tid >> 6;
  const int wm = (w >> 1) * 64, wn = (w & 1) * 64;
  const int fr = lane & 15, fk = (lane >> 4) * 8;
  f32x4 acc[4][4];
#pragma unroll
  for (int i = 0; i < 4; ++i)
#pragma unroll
    for (int j = 0; j < 4; ++j) acc[i][j] = (f32x4){0.f, 0.f, 0.f, 0.f};

  const int i0 = tid, i1 = tid + 256;
  for (int k0 = 0; k0 < K; k0 += 32) {
    async16(A  + (size_t)(m0 + (i0 >> 2)) * lda + k0 + (i0 & 3) * 8, (char*)lsA + i0 * 16);
    async16(A  + (size_t)(m0 + (i1 >> 2)) * lda + k0 + (i1 & 3) * 8, (char*)lsA + i1 * 16);
    async16(Bm + (size_t)(n0 + (i0 >> 2)) * ldb + k0 + (i0 & 3) * 8, (char*)lsB + i0 * 16);
    async16(Bm + (size_t)(n0 + (i1 >> 2)) * ldb + k0 + (i1 & 3) * 8, (char*)lsB + i1 * 16);
    __syncthreads();
    short8 af[4], bfr[4];
#pragma unroll
    for (int mi = 0; mi < 4; ++mi)
      af[mi] = *(const short8*)&lsA[(wm + mi * 16 + fr) * 32 + fk];
#pragma unroll
    for (int ni = 0; ni < 4; ++ni)
      bfr[ni] = *(const short8*)&lsB[(wn + ni * 16 + fr) * 32 + fk];
#pragma unroll
    for (int mi = 0; mi < 4; ++mi)
#pragma unroll
      for (int ni = 0; ni < 4; ++ni)
        acc[mi][ni] = __builtin_amdgcn_mfma_f32_16x16x32_bf16(af[mi], bfr[ni], acc[mi][ni], 0, 0, 0);
    __syncthreads();
  }
#pragma unroll
  for (int mi = 0; mi < 4; ++mi)
#pragma unroll
    for (int ni = 0; ni < 4; ++ni)
#pragma unroll
      for (int r = 0; r < 4; ++r) {
        int gr = m0 + wm + mi * 16 + (lane >> 4) * 4 + r;
        int gc = n0 + wn + ni * 16 + fr;
        float v = acc[mi][ni][r];
        if (EPI == EPI_BF16) ((unsigned short*)Cb)[(size_t)gr * ldc + gc] = f2b(v);
        else                 ((float*)Cb)[(size_t)gr * ldc + gc] = v;
      }
}

// ---------------- fused position attention (v4b) ----------------
// per block: 128 Q-rows x 256 out-cols; K-tiles of 128 over m (32 iters).
// Q and K fragments in REGISTERS (K dbuf-prefetched during PV).
// E-phase reads NO LDS: mfma(Kreg,Qreg) -> __expf -> P write (swizzled LDS).
// V staged via global_load_lds issued post-PV, drained at post-E barrier.
// __launch_bounds__(512,1): 8-wave block = 2 waves/SIMD resident; VGPR cap 256
// (the previous (512,2) capped at 128 -> ~60 regs spilled to scratch, +100MB HBM).
// epilogue: sT = bf16(gpa*acc/l + gca*caT + 2x)
#define QR 128
#define CC 256
#define KT 128
#define NIT (N_ / KT)

__global__ __launch_bounds__(512, 1)
void fused_pa_k(const unsigned short* __restrict__ qkT,   // [B][N][128] (q|k)
                const unsigned short* __restrict__ vmat,  // [B][C][N]
                const unsigned short* __restrict__ caT,   // [B][N][C]
                const unsigned short* __restrict__ xnc,   // [B][N][C]
                const float* __restrict__ gpa_p, const float* __restrict__ gca_p,
                unsigned short* __restrict__ sT) {        // [B][N][C]
  __shared__ unsigned short lsV[CC * KT];     // 64KB, row=256B, 16 granules
  __shared__ unsigned short lsP[QR * KT];     // 32KB, row=256B, 16 granules
  __shared__ float lsL[8][QR];
  __shared__ float invL[QR];

  const int bid = blockIdx.x;
  const int combo = bid & 7;                 // b*2+chalf -> same XCD shares V-half
  const int b = combo >> 1, chalf = combo & 1;
  const int qt = bid >> 3;
  const int n0 = qt * QR, c0 = chalf * CC;

  const int tid = threadIdx.x, lane = tid & 63, w = tid >> 6;
  const int fr = lane & 15, fq = lane >> 4;  // fragment row / k-quarter
  const int wr = w >> 2, wc = w & 3;         // PV wave out-tile 64x64
  const int ms = w * 16;                     // E-phase m-slice

  const unsigned short* qk_b = qkT + (size_t)b * N_ * 128;
  const unsigned short* v_b  = vmat + (size_t)b * C_ * N_;

  // ---- Q fragments in registers (row n0+f*16+fr, k = kk*32+fq*8) ----
  short8 bq[8][2];
#pragma unroll
  for (int f = 0; f < 8; ++f)
#pragma unroll
    for (int kk = 0; kk < 2; ++kk)
      bq[f][kk] = *(const short8*)&qk_b[(size_t)(n0 + f * 16 + fr) * 128 + kk * 32 + fq * 8];

  f32x4 acc[4][4];
#pragma unroll
  for (int i = 0; i < 4; ++i)
#pragma unroll
    for (int j = 0; j < 4; ++j) acc[i][j] = (f32x4){0.f, 0.f, 0.f, 0.f};
  float lsum[8];
#pragma unroll
  for (int f = 0; f < 8; ++f) lsum[f] = 0.f;

  auto stageV = [&](int mt) {
#pragma unroll
    for (int j = 0; j < 8; ++j) {
      int idx = j * 512 + tid;
      int c = idx >> 4, g = idx & 15;
      async16(v_b + (size_t)(c0 + c) * N_ + mt + ((g ^ (c & 7)) << 3), (char*)lsV + idx * 16);
    }
  };
  auto loadK = [&](int mt, short8& k0, short8& k1) {
    const unsigned short* kr = &qk_b[(size_t)(mt + ms + fr) * 128 + 64 + fq * 8];
    k0 = *(const short8*)kr;
    k1 = *(const short8*)(kr + 32);
  };
  // E^T = K . Q^T; wave w owns m-slice [ms, ms+16); all-register inputs.
  auto ephase = [&](short8 k0, short8 k1) {
#pragma unroll
    for (int f = 0; f < 8; ++f) {
      f32x4 e = (f32x4){0.f, 0.f, 0.f, 0.f};
      e = __builtin_amdgcn_mfma_f32_16x16x32_bf16(k0, bq[f][0], e, 0, 0, 0);
      e = __builtin_amdgcn_mfma_f32_16x16x32_bf16(k1, bq[f][1], e, 0, 0, 0);
      float p0 = __expf(e[0]), p1 = __expf(e[1]), p2 = __expf(e[2]), p3 = __expf(e[3]);
      float part = (p0 + p1) + (p2 + p3);
      part += __shfl_xor(part, 16, 64);
      part += __shfl_xor(part, 32, 64);
      lsum[f] += part;
      int n = f * 16 + fr;                     // P row
      int mb = ms + fq * 4;                    // 4 consecutive m
      us4_t pk = { f2b(p0), f2b(p1), f2b(p2), f2b(p3) };
      *(us4_t*)((char*)lsP + n * 256 + ((((mb >> 3) ^ (n & 7)) << 3) + (mb & 7)) * 2) = pk;
    }
  };
  // PV: out[n][c] += P[n][m] * V[c][m]
  auto pvphase = [&]() {
#pragma unroll
    for (int kk4 = 0; kk4 < 4; ++kk4) {
      short8 pa[4], vbf[4];
#pragma unroll
      for (int mi = 0; mi < 4; ++mi) {
        int n = wr * 64 + mi * 16 + fr;
        pa[mi] = *(const short8*)((const char*)lsP + n * 256 + (((kk4 * 4 + fq) ^ (n & 7)) << 4));
      }
#pragma unroll
      for (int ni = 0; ni < 4; ++ni) {
        int c = wc * 64 + ni * 16 + fr;
        vbf[ni] = *(const short8*)((const char*)lsV + c * 256 + (((kk4 * 4 + fq) ^ (c & 7)) << 4));
      }
#pragma unroll
      for (int mi = 0; mi < 4; ++mi)
#pragma unroll
        for (int ni = 0; ni < 4; ++ni)
          acc[mi][ni] = __builtin_amdgcn_mfma_f32_16x16x32_bf16(pa[mi], vbf[ni], acc[mi][ni], 0, 0, 0);
    }
  };

  short8 kA0, kA1, kB0, kB1;
  stageV(0);
  loadK(0, kA0, kA1);
  __syncthreads();                 // V(0) resident, kA waited on first use

  for (int t = 0; t < NIT; t += 2) {
    // ---- even iter t: compute from kA + lsV(t) ----
    ephase(kA0, kA1);              // no LDS reads; covers stageV(t) drain issued last iter
    loadK((t + 1) * KT, kB0, kB1); // prefetch K(t+1) into regs (covered by PV)
    __syncthreads();               // lsP visible; V-stage (issued at t-1 tail) drained
    pvphase();
    __syncthreads();               // lsV reads done -> safe to overwrite
    stageV((t + 1) * KT);          // streams into idle LDS pipe under next E
    // ---- odd iter t+1: compute from kB + lsV(t+1) ----
    ephase(kB0, kB1);
    if (t + 2 < NIT) loadK((t + 2) * KT, kA0, kA1);
    __syncthreads();               // lsP visible; V(t+1) drained
    pvphase();
    __syncthreads();
    if (t + 2 < NIT) stageV((t + 2) * KT);
  }

  // reduce rowsums across waves -> 1/l
  if (lane < 16) {
#pragma unroll
    for (int f = 0; f < 8; ++f) lsL[w][f * 16 + lane] = lsum[f];
  }
  __syncthreads();
  if (tid < QR) {
    float s = 0.f;
#pragma unroll
    for (int ww = 0; ww < 8; ++ww) s += lsL[ww][tid];
    invL[tid] = 1.f / s;
  }
  __syncthreads();

  const float gpa = gpa_p[0], gca = gca_p[0];
#pragma unroll
  for (int mi = 0; mi < 4; ++mi)
#pragma unroll
    for (int ni = 0; ni < 4; ++ni)
#pragma unroll
      for (int r = 0; r < 4; ++r) {
        int nl = wr * 64 + mi * 16 + fq * 4 + r;
        int gn = n0 + nl;
        int gc = c0 + wc * 64 + ni * 16 + fr;
        size_t eo = ((size_t)b * N_ + gn) * C_ + gc;
        float sv = gpa * acc[mi][ni][r] * invL[nl] + gca * b2f(caT[eo]) + 2.f * b2f(xnc[eo]);
        sT[eo] = f2b(sv);
      }
}

// ---------------- channel-attention softmax over ce partials ----------------
__global__ __launch_bounds__(256) void ce_softmax_k(const float* __restrict__ cepart,
                                                    unsigned short* __restrict__ cattn) {
  int wid = threadIdx.x >> 6, lane = threadIdx.x & 63;
  size_t row = (size_t)blockIdx.x * 4 + wid;
  float v[8]; float mn = 3.4e38f;
#pragma unroll
  for (int i = 0; i < 8; ++i) {
    size_t idx = row * C_ + (size_t)(i * 64 + lane);
    float t = cepart[idx] + cepart[idx + 1048576] + cepart[idx + 2097152] + cepart[idx + 3145728];
    v[i] = t; mn = fminf(mn, t);
  }
#pragma unroll
  for (int o = 1; o < 64; o <<= 1) mn = fminf(mn, __shfl_xor(mn, o, 64));
  float s = 0.f, p[8];
#pragma unroll
  for (int i = 0; i < 8; ++i) { p[i] = expf(mn - v[i]); s += p[i]; }
#pragma unroll
  for (int o = 1; o < 64; o <<= 1) s += __shfl_xor(s, o, 64);
  float inv = 1.f / s;
  unsigned short* orow = cattn + row * C_;
#pragma unroll
  for (int i = 0; i < 8; ++i) orow[i * 64 + lane] = f2b(p[i] * inv);
}

// ---------------- BN statistics (two stage, deterministic) ----------------
__global__ __launch_bounds__(256) void bn_part_k(const float* __restrict__ yT,
                                                 float* __restrict__ part) {
  int p = blockIdx.x, t = threadIdx.x;
  const float* base = yT + (size_t)p * 256 * C_;
  float s0 = 0, q0 = 0, s1 = 0, q1 = 0;
  for (int r = 0; r < 256; ++r) {
    float a = base[(size_t)r * C_ + t];
    float b = base[(size_t)r * C_ + t + 256];
    s0 += a; q0 += a * a; s1 += b; q1 += b * b;
  }
  float* pp = part + (size_t)p * 1024;
  pp[t] = s0; pp[t + 256] = s1; pp[t + 512] = q0; pp[t + 768] = q1;
}

__global__ __launch_bounds__(256) void bn_final_k(const float* __restrict__ part,
                                                  const float* __restrict__ bns,
                                                  const float* __restrict__ bnb,
                                                  float* __restrict__ ab) {
  int t = threadIdx.x;
#pragma unroll
  for (int cc = 0; cc < 2; ++cc) {
    int c = t + cc * 256;
    float s = 0, q = 0;
    for (int p = 0; p < 64; ++p) { s += part[p * 1024 + c]; q += part[p * 1024 + 512 + c]; }
    float mean = s * (1.f / 16384.f);
    float var  = q * (1.f / 16384.f) - mean * mean;
    float istd = rsqrtf(var + BN_EPS);
    float a = bns[c] * istd;
    float b = bnb[c] - mean * a;
    ab[c * 2] = a; ab[c * 2 + 1] = b;
  }
}

__global__ __launch_bounds__(256) void bn_apply_k(const float* __restrict__ yT,
                                                  const float* __restrict__ ab,
                                                  float* __restrict__ out) {
  __shared__ float tile[64][65];
  int n0 = blockIdx.x * 64, o0 = blockIdx.y * 64, b = blockIdx.z;
  const float* yb = yT + ((size_t)b * N_ + n0) * C_ + o0;
#pragma unroll
  for (int j = 0; j < 16; ++j) {
    int lin = j * 256 + threadIdx.x;
    int rr = lin >> 6, cc = lin & 63;
    float v = yb[(size_t)rr * C_ + cc];
    float a = ab[(o0 + cc) * 2], bb = ab[(o0 + cc) * 2 + 1];
    tile[cc][rr] = fmaxf(v * a + bb, 0.f);
  }
  __syncthreads();
  float* ob = out + ((size_t)b * C_ + o0) * N_ + n0;
#pragma unroll
  for (int j = 0; j < 16; ++j) {
    int lin = j * 256 + threadIdx.x;
    int rr = lin >> 6, cc = lin & 63;
    ob[(size_t)rr * N_ + cc] = tile[rr][cc];
  }
}

// ---------------- host launch ----------------

extern "C" void kernel_launch(void* const* d_in, const int* in_sizes, int n_in,
                              void* d_out, int out_size, void* d_ws, size_t ws_size,
                              hipStream_t stream) {
  (void)in_sizes; (void)n_in; (void)out_size; (void)ws_size;
  const float* x   = (const float*)d_in[0];
  const float* wq  = (const float*)d_in[1];
  const float* wk  = (const float*)d_in[2];
  const float* wv  = (const float*)d_in[3];
  const float* wf  = (const float*)d_in[4];
  const float* gpa = (const float*)d_in[5];
  const float* gca = (const float*)d_in[6];
  const float* bns = (const float*)d_in[7];
  const float* bnb = (const float*)d_in[8];
  float* out = (float*)d_out;

  char* ws = (char*)d_ws;
  size_t off = 0;
  auto carve = [&](size_t bytes) -> char* {
    off = (off + 255) & ~(size_t)255;
    char* p = ws + off; off += bytes; return p;
  };

  unsigned short* xcn   = (unsigned short*)carve((size_t)B_ * C_ * N_ * 2);  // reused as sT
  unsigned short* xnc   = (unsigned short*)carve((size_t)B_ * C_ * N_ * 2);
  unsigned short* wqkb  = (unsigned short*)carve(128 * 512 * 2);
  unsigned short* wvb   = (unsigned short*)carve(512 * 512 * 2);
  unsigned short* wfb   = (unsigned short*)carve(512 * 512 * 2);
  unsigned short* qkT   = (unsigned short*)carve((size_t)B_ * N_ * 128 * 2);
  unsigned short* vmat  = (unsigned short*)carve((size_t)B_ * C_ * N_ * 2);
  float*          cepart= (float*)carve((size_t)4 * B_ * 512 * 512 * 4);     // reused as yT
  unsigned short* cattn = (unsigned short*)carve((size_t)B_ * 512 * 512 * 2);
  unsigned short* caT   = (unsigned short*)carve((size_t)B_ * N_ * C_ * 2);
  float*          bnpart= (float*)carve((size_t)64 * 1024 * 4);
  float*          abv   = (float*)carve(512 * 2 * 4);

  float* yT = cepart;                 // overlay: cepart dead after ce_softmax
  unsigned short* sT = xcn;           // overlay: xcn dead after ce GEMM

  // 1) conversions
  convert_x_k<<<dim3(C_ / 64, N_ / 64, B_), 256, 0, stream>>>(x, xcn, xnc);
  convert_w_k<<<dim3(1024), 256, 0, stream>>>(wq, wk, wv, wf, wqkb, wvb, wfb);

  // 2) qkT[n][0:128] = xnc @ wqk^T
  gemm_bt<EPI_BF16><<<dim3(32, 1, 4), 256, 0, stream>>>(
      xnc, 512, (size_t)N_ * C_, wqkb, 512, 0,
      qkT, 128, (size_t)N_ * 128 * 2, 512);

  // 3) v[c][m] = wv @ x
  gemm_bt<EPI_BF16><<<dim3(4, 32, 4), 256, 0, stream>>>(
      wvb, 512, 0, xnc, 512, (size_t)N_ * C_,
      vmat, N_, (size_t)C_ * N_ * 2, 512);

  // 4) ce partials = X X^T (split-K x4)
  gemm_bt<EPI_F32, true><<<dim3(4, 4, 16), 256, 0, stream>>>(
      xcn, N_, (size_t)C_ * N_, xcn, N_, (size_t)C_ * N_,
      cepart, 512, (size_t)512 * 512 * 4, 1024);

  // 5) channel softmax -> cattn bf16
  ce_softmax_k<<<dim3(B_ * 512 / 4), 256, 0, stream>>>(cepart, cattn);

  // 6) caT[n][c] = xnc @ cattn^T
  gemm_bt<EPI_BF16><<<dim3(32, 4, 4), 256, 0, stream>>>(
      xnc, 512, (size_t)N_ * C_, cattn, 512, (size_t)512 * 512,
      caT, 512, (size_t)N_ * C_ * 2, 512);

  // 7) fused position attention + combine epilogue -> sT
  fused_pa_k<<<dim3(256), 512, 0, stream>>>(qkT, vmat, caT, xnc, gpa, gca, sT);

  // 8) yT[n][o] = sT @ wfuse^T (fp32)
  gemm_bt<EPI_F32><<<dim3(32, 4, 4), 256, 0, stream>>>(
      sT, 512, (size_t)N_ * C_, wfb, 512, 0,
      yT, 512, (size_t)N_ * C_ * 4, 512);

  // 9) BN stats + apply + transpose + relu
  bn_part_k<<<dim3(64), 256, 0, stream>>>(yT, bnpart);
  bn_final_k<<<dim3(1), 256, 0, stream>>>(bnpart, bns, bnb, abv);
  bn_apply_k<<<dim3(N_ / 64, C_ / 64, B_), 256, 0, stream>>>(yT, abv, out);
}

// Round 9
// 319.819 us; speedup vs baseline: 1.0008x; 1.0003x over previous
//
#include <hip/hip_runtime.h>
#include <cstdint>
#include <cstddef>

#define B_   4
#define C_   512
#define N_   4096
#define BN_EPS 1e-5f

typedef __attribute__((ext_vector_type(8))) short short8;
typedef __attribute__((ext_vector_type(8))) unsigned short ushort8;
typedef __attribute__((ext_vector_type(4))) unsigned short us4_t;
typedef __attribute__((ext_vector_type(4))) float f32x4;

__device__ __forceinline__ unsigned short f2b(float f) {
  union { float f; unsigned u; } v; v.f = f;
  unsigned u = v.u;
  return (unsigned short)((u + 0x7fffu + ((u >> 16) & 1u)) >> 16);
}
__device__ __forceinline__ float b2f(unsigned short h) {
  union { unsigned u; float f; } v; v.u = ((unsigned)h) << 16;
  return v.f;
}
__device__ __forceinline__ void async16(const void* g, void* l) {
  __builtin_amdgcn_global_load_lds((const __attribute__((address_space(1))) void*)g,
                                   (__attribute__((address_space(3))) void*)l, 16, 0, 0);
}

// ---------------- conversion kernels ----------------

__global__ __launch_bounds__(256) void convert_x_k(const float* __restrict__ x,
                                                   unsigned short* __restrict__ xcn,
                                                   unsigned short* __restrict__ xnc) {
  __shared__ float tile[64][65];
  int c0 = blockIdx.x * 64, n0 = blockIdx.y * 64, b = blockIdx.z;
  const float* xb = x + ((size_t)b * C_ + c0) * N_ + n0;
  unsigned short* cn = xcn + ((size_t)b * C_ + c0) * N_ + n0;
#pragma unroll
  for (int j = 0; j < 16; ++j) {
    int lin = j * 256 + threadIdx.x;
    int rr = lin >> 6, cc = lin & 63;
    float v = xb[(size_t)rr * N_ + cc];
    cn[(size_t)rr * N_ + cc] = f2b(v);
    tile[cc][rr] = v;
  }
  __syncthreads();
  unsigned short* nc = xnc + ((size_t)b * N_ + n0) * C_ + c0;
#pragma unroll
  for (int j = 0; j < 16; ++j) {
    int lin = j * 256 + threadIdx.x;
    int rr = lin >> 6, cc = lin & 63;
    nc[(size_t)rr * C_ + cc] = f2b(tile[rr][cc]);
  }
}

__global__ __launch_bounds__(256) void convert_w_k(const float* __restrict__ wq, const float* __restrict__ wk,
                                                   const float* __restrict__ wv, const float* __restrict__ wf,
                                                   unsigned short* __restrict__ wqk,
                                                   unsigned short* __restrict__ wvb,
                                                   unsigned short* __restrict__ wfb) {
  int i = blockIdx.x * 256 + threadIdx.x;
  if (i < 128 * 512) {
    int row = i >> 9, col = i & 511;
    float v = (row < 64) ? wq[row * 512 + col] : wk[(row - 64) * 512 + col];
    wqk[i] = f2b(v);
  }
  wvb[i] = f2b(wv[i]);
  wfb[i] = f2b(wf[i]);
}

// ---------------- generic MFMA GEMM:  C[m,n] = sum_k A[m,k] * B'[n,k] ----------------

enum { EPI_BF16 = 0, EPI_F32 = 1 };

template<int EPI, bool SPLITK = false>
__global__ __launch_bounds__(256)
void gemm_bt(const unsigned short* __restrict__ A, size_t lda, size_t sA,
             const unsigned short* __restrict__ Bm, size_t ldb, size_t sB,
             void* __restrict__ Cv, size_t ldc, size_t sCbytes, int K) {
  const int bz = blockIdx.z;
  const int m0 = blockIdx.x * 128, n0 = blockIdx.y * 128;
  char* Cb;
  if (SPLITK) {
    int bidx = bz & 3, ch = bz >> 2;
    A  += (size_t)bidx * sA + (size_t)ch * (size_t)K;
    Bm += (size_t)bidx * sB + (size_t)ch * (size_t)K;
    Cb = (char*)Cv + (size_t)bidx * sCbytes + (size_t)ch * 4u * sCbytes;
  } else {
    A  += (size_t)bz * sA;
    Bm += (size_t)bz * sB;
    Cb = (char*)Cv + (size_t)bz * sCbytes;
  }
  __shared__ unsigned short lsA[128 * 32];
  __shared__ unsigned short lsB[128 * 32];
  const int tid = threadIdx.x, lane = tid & 63, w = tid >> 6;
  const int wm = (w >> 1) * 64, wn = (w & 1) * 64;
  const int fr = lane & 15, fk = (lane >> 4) * 8;
  f32x4 acc[4][4];
#pragma unroll
  for (int i = 0; i < 4; ++i)
#pragma unroll
    for (int j = 0; j < 4; ++j) acc[i][j] = (f32x4){0.f, 0.f, 0.f, 0.f};

  const int i0 = tid, i1 = tid + 256;
  for (int k0 = 0; k0 < K; k0 += 32) {
    async16(A  + (size_t)(m0 + (i0 >> 2)) * lda + k0 + (i0 & 3) * 8, (char*)lsA + i0 * 16);
    async16(A  + (size_t)(m0 + (i1 >> 2)) * lda + k0 + (i1 & 3) * 8, (char*)lsA + i1 * 16);
    async16(Bm + (size_t)(n0 + (i0 >> 2)) * ldb + k0 + (i0 & 3) * 8, (char*)lsB + i0 * 16);
    async16(Bm + (size_t)(n0 + (i1 >> 2)) * ldb + k0 + (i1 & 3) * 8, (char*)lsB + i1 * 16);
    __syncthreads();
    short8 af[4], bfr[4];
#pragma unroll
    for (int mi = 0; mi < 4; ++mi)
      af[mi] = *(const short8*)&lsA[(wm + mi * 16 + fr) * 32 + fk];
#pragma unroll
    for (int ni = 0; ni < 4; ++ni)
      bfr[ni] = *(const short8*)&lsB[(wn + ni * 16 + fr) * 32 + fk];
#pragma unroll
    for (int mi = 0; mi < 4; ++mi)
#pragma unroll
      for (int ni = 0; ni < 4; ++ni)
        acc[mi][ni] = __builtin_amdgcn_mfma_f32_16x16x32_bf16(af[mi], bfr[ni], acc[mi][ni], 0, 0, 0);
    __syncthreads();
  }
#pragma unroll
  for (int mi = 0; mi < 4; ++mi)
#pragma unroll
    for (int ni = 0; ni < 4; ++ni)
#pragma unroll
      for (int r = 0; r < 4; ++r) {
        int gr = m0 + wm + mi * 16 + (lane >> 4) * 4 + r;
        int gc = n0 + wn + ni * 16 + fr;
        float v = acc[mi][ni][r];
        if (EPI == EPI_BF16) ((unsigned short*)Cb)[(size_t)gr * ldc + gc] = f2b(v);
        else                 ((float*)Cb)[(size_t)gr * ldc + gc] = v;
      }
}

// ---------------- fused position attention (v4c) ----------------
// per block: 128 Q-rows x 256 out-cols; K-tiles of 128 over m (32 iters).
// Q and K fragments in REGISTERS (K dbuf-prefetched during PV).
// E-phase reads NO LDS: mfma(Kreg,Qreg) -> __expf -> P write (swizzled LDS).
// V staged via global_load_lds issued post-PV, drained at post-E barrier.
// amdgpu_waves_per_eu(2,2): 100KB LDS pins 1 block/CU = 2 waves/SIMD anyway;
// pinning max=2 lifts the VGPR allocator cap to 256 (demand ~185) — the
// launch_bounds-based attempts left the cap at 128 and spilled ~50MB/dispatch.
// epilogue: sT = bf16(gpa*acc/l + gca*caT + 2x)
#define QR 128
#define CC 256
#define KT 128
#define NIT (N_ / KT)

__global__ __attribute__((amdgpu_waves_per_eu(2, 2))) __launch_bounds__(512)
void fused_pa_k(const unsigned short* __restrict__ qkT,   // [B][N][128] (q|k)
                const unsigned short* __restrict__ vmat,  // [B][C][N]
                const unsigned short* __restrict__ caT,   // [B][N][C]
                const unsigned short* __restrict__ xnc,   // [B][N][C]
                const float* __restrict__ gpa_p, const float* __restrict__ gca_p,
                unsigned short* __restrict__ sT) {        // [B][N][C]
  __shared__ unsigned short lsV[CC * KT];     // 64KB, row=256B, 16 granules
  __shared__ unsigned short lsP[QR * KT];     // 32KB, row=256B, 16 granules
  __shared__ float lsL[8][QR];
  __shared__ float invL[QR];

  const int bid = blockIdx.x;
  const int combo = bid & 7;                 // b*2+chalf -> same XCD shares V-half
  const int b = combo >> 1, chalf = combo & 1;
  const int qt = bid >> 3;
  const int n0 = qt * QR, c0 = chalf * CC;

  const int tid = threadIdx.x, lane = tid & 63, w = tid >> 6;
  const int fr = lane & 15, fq = lane >> 4;  // fragment row / k-quarter
  const int wr = w >> 2, wc = w & 3;         // PV wave out-tile 64x64
  const int ms = w * 16;                     // E-phase m-slice

  const unsigned short* qk_b = qkT + (size_t)b * N_ * 128;
  const unsigned short* v_b  = vmat + (size_t)b * C_ * N_;

  // ---- Q fragments in registers (row n0+f*16+fr, k = kk*32+fq*8) ----
  short8 bq[8][2];
#pragma unroll
  for (int f = 0; f < 8; ++f)
#pragma unroll
    for (int kk = 0; kk < 2; ++kk)
      bq[f][kk] = *(const short8*)&qk_b[(size_t)(n0 + f * 16 + fr) * 128 + kk * 32 + fq * 8];

  f32x4 acc[4][4];
#pragma unroll
  for (int i = 0; i < 4; ++i)
#pragma unroll
    for (int j = 0; j < 4; ++j) acc[i][j] = (f32x4){0.f, 0.f, 0.f, 0.f};
  float lsum[8];
#pragma unroll
  for (int f = 0; f < 8; ++f) lsum[f] = 0.f;

  auto stageV = [&](int mt) {
#pragma unroll
    for (int j = 0; j < 8; ++j) {
      int idx = j * 512 + tid;
      int c = idx >> 4, g = idx & 15;
      async16(v_b + (size_t)(c0 + c) * N_ + mt + ((g ^ (c & 7)) << 3), (char*)lsV + idx * 16);
    }
  };
  auto loadK = [&](int mt, short8& k0, short8& k1) {
    const unsigned short* kr = &qk_b[(size_t)(mt + ms + fr) * 128 + 64 + fq * 8];
    k0 = *(const short8*)kr;
    k1 = *(const short8*)(kr + 32);
  };
  // E^T = K . Q^T; wave w owns m-slice [ms, ms+16); all-register inputs.
  auto ephase = [&](short8 k0, short8 k1) {
#pragma unroll
    for (int f = 0; f < 8; ++f) {
      f32x4 e = (f32x4){0.f, 0.f, 0.f, 0.f};
      e = __builtin_amdgcn_mfma_f32_16x16x32_bf16(k0, bq[f][0], e, 0, 0, 0);
      e = __builtin_amdgcn_mfma_f32_16x16x32_bf16(k1, bq[f][1], e, 0, 0, 0);
      float p0 = __expf(e[0]), p1 = __expf(e[1]), p2 = __expf(e[2]), p3 = __expf(e[3]);
      float part = (p0 + p1) + (p2 + p3);
      part += __shfl_xor(part, 16, 64);
      part += __shfl_xor(part, 32, 64);
      lsum[f] += part;
      int n = f * 16 + fr;                     // P row
      int mb = ms + fq * 4;                    // 4 consecutive m
      us4_t pk = { f2b(p0), f2b(p1), f2b(p2), f2b(p3) };
      *(us4_t*)((char*)lsP + n * 256 + ((((mb >> 3) ^ (n & 7)) << 3) + (mb & 7)) * 2) = pk;
    }
  };
  // PV: out[n][c] += P[n][m] * V[c][m]
  auto pvphase = [&]() {
#pragma unroll
    for (int kk4 = 0; kk4 < 4; ++kk4) {
      short8 pa[4], vbf[4];
#pragma unroll
      for (int mi = 0; mi < 4; ++mi) {
        int n = wr * 64 + mi * 16 + fr;
        pa[mi] = *(const short8*)((const char*)lsP + n * 256 + (((kk4 * 4 + fq) ^ (n & 7)) << 4));
      }
#pragma unroll
      for (int ni = 0; ni < 4; ++ni) {
        int c = wc * 64 + ni * 16 + fr;
        vbf[ni] = *(const short8*)((const char*)lsV + c * 256 + (((kk4 * 4 + fq) ^ (c & 7)) << 4));
      }
#pragma unroll
      for (int mi = 0; mi < 4; ++mi)
#pragma unroll
        for (int ni = 0; ni < 4; ++ni)
          acc[mi][ni] = __builtin_amdgcn_mfma_f32_16x16x32_bf16(pa[mi], vbf[ni], acc[mi][ni], 0, 0, 0);
    }
  };

  short8 kA0, kA1, kB0, kB1;
  stageV(0);
  loadK(0, kA0, kA1);
  __syncthreads();                 // V(0) resident, kA waited on first use

  for (int t = 0; t < NIT; t += 2) {
    // ---- even iter t: compute from kA + lsV(t) ----
    ephase(kA0, kA1);              // no LDS reads; covers stageV(t) drain issued last iter
    loadK((t + 1) * KT, kB0, kB1); // prefetch K(t+1) into regs (covered by PV)
    __syncthreads();               // lsP visible; V-stage (issued at t-1 tail) drained
    pvphase();
    __syncthreads();               // lsV reads done -> safe to overwrite
    stageV((t + 1) * KT);          // streams into idle LDS pipe under next E
    // ---- odd iter t+1: compute from kB + lsV(t+1) ----
    ephase(kB0, kB1);
    if (t + 2 < NIT) loadK((t + 2) * KT, kA0, kA1);
    __syncthreads();               // lsP visible; V(t+1) drained
    pvphase();
    __syncthreads();
    if (t + 2 < NIT) stageV((t + 2) * KT);
  }

  // reduce rowsums across waves -> 1/l
  if (lane < 16) {
#pragma unroll
    for (int f = 0; f < 8; ++f) lsL[w][f * 16 + lane] = lsum[f];
  }
  __syncthreads();
  if (tid < QR) {
    float s = 0.f;
#pragma unroll
    for (int ww = 0; ww < 8; ++ww) s += lsL[ww][tid];
    invL[tid] = 1.f / s;
  }
  __syncthreads();

  const float gpa = gpa_p[0], gca = gca_p[0];
#pragma unroll
  for (int mi = 0; mi < 4; ++mi)
#pragma unroll
    for (int ni = 0; ni < 4; ++ni)
#pragma unroll
      for (int r = 0; r < 4; ++r) {
        int nl = wr * 64 + mi * 16 + fq * 4 + r;
        int gn = n0 + nl;
        int gc = c0 + wc * 64 + ni * 16 + fr;
        size_t eo = ((size_t)b * N_ + gn) * C_ + gc;
        float sv = gpa * acc[mi][ni][r] * invL[nl] + gca * b2f(caT[eo]) + 2.f * b2f(xnc[eo]);
        sT[eo] = f2b(sv);
      }
}

// ---------------- channel-attention softmax over ce partials ----------------
__global__ __launch_bounds__(256) void ce_softmax_k(const float* __restrict__ cepart,
                                                    unsigned short* __restrict__ cattn) {
  int wid = threadIdx.x >> 6, lane = threadIdx.x & 63;
  size_t row = (size_t)blockIdx.x * 4 + wid;
  float v[8]; float mn = 3.4e38f;
#pragma unroll
  for (int i = 0; i < 8; ++i) {
    size_t idx = row * C_ + (size_t)(i * 64 + lane);
    float t = cepart[idx] + cepart[idx + 1048576] + cepart[idx + 2097152] + cepart[idx + 3145728];
    v[i] = t; mn = fminf(mn, t);
  }
#pragma unroll
  for (int o = 1; o < 64; o <<= 1) mn = fminf(mn, __shfl_xor(mn, o, 64));
  float s = 0.f, p[8];
#pragma unroll
  for (int i = 0; i < 8; ++i) { p[i] = expf(mn - v[i]); s += p[i]; }
#pragma unroll
  for (int o = 1; o < 64; o <<= 1) s += __shfl_xor(s, o, 64);
  float inv = 1.f / s;
  unsigned short* orow = cattn + row * C_;
#pragma unroll
  for (int i = 0; i < 8; ++i) orow[i * 64 + lane] = f2b(p[i] * inv);
}

// ---------------- BN statistics (two stage, deterministic) ----------------
__global__ __launch_bounds__(256) void bn_part_k(const float* __restrict__ yT,
                                                 float* __restrict__ part) {
  int p = blockIdx.x, t = threadIdx.x;
  const float* base = yT + (size_t)p * 256 * C_;
  float s0 = 0, q0 = 0, s1 = 0, q1 = 0;
  for (int r = 0; r < 256; ++r) {
    float a = base[(size_t)r * C_ + t];
    float b = base[(size_t)r * C_ + t + 256];
    s0 += a; q0 += a * a; s1 += b; q1 += b * b;
  }
  float* pp = part + (size_t)p * 1024;
  pp[t] = s0; pp[t + 256] = s1; pp[t + 512] = q0; pp[t + 768] = q1;
}

__global__ __launch_bounds__(256) void bn_final_k(const float* __restrict__ part,
                                                  const float* __restrict__ bns,
                                                  const float* __restrict__ bnb,
                                                  float* __restrict__ ab) {
  int t = threadIdx.x;
#pragma unroll
  for (int cc = 0; cc < 2; ++cc) {
    int c = t + cc * 256;
    float s = 0, q = 0;
    for (int p = 0; p < 64; ++p) { s += part[p * 1024 + c]; q += part[p * 1024 + 512 + c]; }
    float mean = s * (1.f / 16384.f);
    float var  = q * (1.f / 16384.f) - mean * mean;
    float istd = rsqrtf(var + BN_EPS);
    float a = bns[c] * istd;
    float b = bnb[c] - mean * a;
    ab[c * 2] = a; ab[c * 2 + 1] = b;
  }
}

__global__ __launch_bounds__(256) void bn_apply_k(const float* __restrict__ yT,
                                                  const float* __restrict__ ab,
                                                  float* __restrict__ out) {
  __shared__ float tile[64][65];
  int n0 = blockIdx.x * 64, o0 = blockIdx.y * 64, b = blockIdx.z;
  const float* yb = yT + ((size_t)b * N_ + n0) * C_ + o0;
#pragma unroll
  for (int j = 0; j < 16; ++j) {
    int lin = j * 256 + threadIdx.x;
    int rr = lin >> 6, cc = lin & 63;
    float v = yb[(size_t)rr * C_ + cc];
    float a = ab[(o0 + cc) * 2], bb = ab[(o0 + cc) * 2 + 1];
    tile[cc][rr] = fmaxf(v * a + bb, 0.f);
  }
  __syncthreads();
  float* ob = out + ((size_t)b * C_ + o0) * N_ + n0;
#pragma unroll
  for (int j = 0; j < 16; ++j) {
    int lin = j * 256 + threadIdx.x;
    int rr = lin >> 6, cc = lin & 63;
    ob[(size_t)rr * N_ + cc] = tile[rr][cc];
  }
}

// ---------------- host launch ----------------

extern "C" void kernel_launch(void* const* d_in, const int* in_sizes, int n_in,
                              void* d_out, int out_size, void* d_ws, size_t ws_size,
                              hipStream_t stream) {
  (void)in_sizes; (void)n_in; (void)out_size; (void)ws_size;
  const float* x   = (const float*)d_in[0];
  const float* wq  = (const float*)d_in[1];
  const float* wk  = (const float*)d_in[2];
  const float* wv  = (const float*)d_in[3];
  const float* wf  = (const float*)d_in[4];
  const float* gpa = (const float*)d_in[5];
  const float* gca = (const float*)d_in[6];
  const float* bns = (const float*)d_in[7];
  const float* bnb = (const float*)d_in[8];
  float* out = (float*)d_out;

  char* ws = (char*)d_ws;
  size_t off = 0;
  auto carve = [&](size_t bytes) -> char* {
    off = (off + 255) & ~(size_t)255;
    char* p = ws + off; off += bytes; return p;
  };

  unsigned short* xcn   = (unsigned short*)carve((size_t)B_ * C_ * N_ * 2);  // reused as sT
  unsigned short* xnc   = (unsigned short*)carve((size_t)B_ * C_ * N_ * 2);
  unsigned short* wqkb  = (unsigned short*)carve(128 * 512 * 2);
  unsigned short* wvb   = (unsigned short*)carve(512 * 512 * 2);
  unsigned short* wfb   = (unsigned short*)carve(512 * 512 * 2);
  unsigned short* qkT   = (unsigned short*)carve((size_t)B_ * N_ * 128 * 2);
  unsigned short* vmat  = (unsigned short*)carve((size_t)B_ * C_ * N_ * 2);
  float*          cepart= (float*)carve((size_t)4 * B_ * 512 * 512 * 4);     // reused as yT
  unsigned short* cattn = (unsigned short*)carve((size_t)B_ * 512 * 512 * 2);
  unsigned short* caT   = (unsigned short*)carve((size_t)B_ * N_ * C_ * 2);
  float*          bnpart= (float*)carve((size_t)64 * 1024 * 4);
  float*          abv   = (float*)carve(512 * 2 * 4);

  float* yT = cepart;                 // overlay: cepart dead after ce_softmax
  unsigned short* sT = xcn;           // overlay: xcn dead after ce GEMM

  // 1) conversions
  convert_x_k<<<dim3(C_ / 64, N_ / 64, B_), 256, 0, stream>>>(x, xcn, xnc);
  convert_w_k<<<dim3(1024), 256, 0, stream>>>(wq, wk, wv, wf, wqkb, wvb, wfb);

  // 2) qkT[n][0:128] = xnc @ wqk^T
  gemm_bt<EPI_BF16><<<dim3(32, 1, 4), 256, 0, stream>>>(
      xnc, 512, (size_t)N_ * C_, wqkb, 512, 0,
      qkT, 128, (size_t)N_ * 128 * 2, 512);

  // 3) v[c][m] = wv @ x
  gemm_bt<EPI_BF16><<<dim3(4, 32, 4), 256, 0, stream>>>(
      wvb, 512, 0, xnc, 512, (size_t)N_ * C_,
      vmat, N_, (size_t)C_ * N_ * 2, 512);

  // 4) ce partials = X X^T (split-K x4)
  gemm_bt<EPI_F32, true><<<dim3(4, 4, 16), 256, 0, stream>>>(
      xcn, N_, (size_t)C_ * N_, xcn, N_, (size_t)C_ * N_,
      cepart, 512, (size_t)512 * 512 * 4, 1024);

  // 5) channel softmax -> cattn bf16
  ce_softmax_k<<<dim3(B_ * 512 / 4), 256, 0, stream>>>(cepart, cattn);

  // 6) caT[n][c] = xnc @ cattn^T
  gemm_bt<EPI_BF16><<<dim3(32, 4, 4), 256, 0, stream>>>(
      xnc, 512, (size_t)N_ * C_, cattn, 512, (size_t)512 * 512,
      caT, 512, (size_t)N_ * C_ * 2, 512);

  // 7) fused position attention + combine epilogue -> sT
  fused_pa_k<<<dim3(256), 512, 0, stream>>>(qkT, vmat, caT, xnc, gpa, gca, sT);

  // 8) yT[n][o] = sT @ wfuse^T (fp32)
  gemm_bt<EPI_F32><<<dim3(32, 4, 4), 256, 0, stream>>>(
      sT, 512, (size_t)N_ * C_, wfb, 512, 0,
      yT, 512, (size_t)N_ * C_ * 4, 512);

  // 9) BN stats + apply + transpose + relu
  bn_part_k<<<dim3(64), 256, 0, stream>>>(yT, bnpart);
  bn_final_k<<<dim3(1), 256, 0, stream>>>(bnpart, bns, bnb, abv);
  bn_apply_k<<<dim3(N_ / 64, C_ / 64, B_), 256, 0, stream>>>(yT, abv, out);
}

// Round 10
// 257.624 us; speedup vs baseline: 1.2424x; 1.2414x over previous
//
#include <hip/hip_runtime.h>
#include <cstdint>
#include <cstddef>

#define B_   4
#define C_   512
#define N_   4096
#define BN_EPS 1e-5f

typedef __attribute__((ext_vector_type(8))) short short8;
typedef __attribute__((ext_vector_type(8))) unsigned short ushort8;
typedef __attribute__((ext_vector_type(4))) unsigned short us4_t;
typedef __attribute__((ext_vector_type(4))) float f32x4;

__device__ __forceinline__ unsigned short f2b(float f) {
  union { float f; unsigned u; } v; v.f = f;
  unsigned u = v.u;
  return (unsigned short)((u + 0x7fffu + ((u >> 16) & 1u)) >> 16);
}
__device__ __forceinline__ float b2f(unsigned short h) {
  union { unsigned u; float f; } v; v.u = ((unsigned)h) << 16;
  return v.f;
}
__device__ __forceinline__ void async16(const void* g, void* l) {
  __builtin_amdgcn_global_load_lds((const __attribute__((address_space(1))) void*)g,
                                   (__attribute__((address_space(3))) void*)l, 16, 0, 0);
}

// ---------------- conversion kernels ----------------

__global__ __launch_bounds__(256) void convert_x_k(const float* __restrict__ x,
                                                   unsigned short* __restrict__ xcn,
                                                   unsigned short* __restrict__ xnc) {
  __shared__ float tile[64][65];
  int c0 = blockIdx.x * 64, n0 = blockIdx.y * 64, b = blockIdx.z;
  const float* xb = x + ((size_t)b * C_ + c0) * N_ + n0;
  unsigned short* cn = xcn + ((size_t)b * C_ + c0) * N_ + n0;
#pragma unroll
  for (int j = 0; j < 16; ++j) {
    int lin = j * 256 + threadIdx.x;
    int rr = lin >> 6, cc = lin & 63;
    float v = xb[(size_t)rr * N_ + cc];
    cn[(size_t)rr * N_ + cc] = f2b(v);
    tile[cc][rr] = v;
  }
  __syncthreads();
  unsigned short* nc = xnc + ((size_t)b * N_ + n0) * C_ + c0;
#pragma unroll
  for (int j = 0; j < 16; ++j) {
    int lin = j * 256 + threadIdx.x;
    int rr = lin >> 6, cc = lin & 63;
    nc[(size_t)rr * C_ + cc] = f2b(tile[rr][cc]);
  }
}

__global__ __launch_bounds__(256) void convert_w_k(const float* __restrict__ wq, const float* __restrict__ wk,
                                                   const float* __restrict__ wv, const float* __restrict__ wf,
                                                   unsigned short* __restrict__ wqk,
                                                   unsigned short* __restrict__ wvb,
                                                   unsigned short* __restrict__ wfb) {
  int i = blockIdx.x * 256 + threadIdx.x;
  if (i < 128 * 512) {
    int row = i >> 9, col = i & 511;
    float v = (row < 64) ? wq[row * 512 + col] : wk[(row - 64) * 512 + col];
    wqk[i] = f2b(v);
  }
  wvb[i] = f2b(wv[i]);
  wfb[i] = f2b(wf[i]);
}

// ---------------- generic MFMA GEMM:  C[m,n] = sum_k A[m,k] * B'[n,k] ----------------

enum { EPI_BF16 = 0, EPI_F32 = 1 };

template<int EPI, bool SPLITK = false>
__global__ __launch_bounds__(256)
void gemm_bt(const unsigned short* __restrict__ A, size_t lda, size_t sA,
             const unsigned short* __restrict__ Bm, size_t ldb, size_t sB,
             void* __restrict__ Cv, size_t ldc, size_t sCbytes, int K) {
  const int bz = blockIdx.z;
  const int m0 = blockIdx.x * 128, n0 = blockIdx.y * 128;
  char* Cb;
  if (SPLITK) {
    int bidx = bz & 3, ch = bz >> 2;
    A  += (size_t)bidx * sA + (size_t)ch * (size_t)K;
    Bm += (size_t)bidx * sB + (size_t)ch * (size_t)K;
    Cb = (char*)Cv + (size_t)bidx * sCbytes + (size_t)ch * 4u * sCbytes;
  } else {
    A  += (size_t)bz * sA;
    Bm += (size_t)bz * sB;
    Cb = (char*)Cv + (size_t)bz * sCbytes;
  }
  __shared__ unsigned short lsA[128 * 32];
  __shared__ unsigned short lsB[128 * 32];
  const int tid = threadIdx.x, lane = tid & 63, w = tid >> 6;
  const int wm = (w >> 1) * 64, wn = (w & 1) * 64;
  const int fr = lane & 15, fk = (lane >> 4) * 8;
  f32x4 acc[4][4];
#pragma unroll
  for (int i = 0; i < 4; ++i)
#pragma unroll
    for (int j = 0; j < 4; ++j) acc[i][j] = (f32x4){0.f, 0.f, 0.f, 0.f};

  const int i0 = tid, i1 = tid + 256;
  for (int k0 = 0; k0 < K; k0 += 32) {
    async16(A  + (size_t)(m0 + (i0 >> 2)) * lda + k0 + (i0 & 3) * 8, (char*)lsA + i0 * 16);
    async16(A  + (size_t)(m0 + (i1 >> 2)) * lda + k0 + (i1 & 3) * 8, (char*)lsA + i1 * 16);
    async16(Bm + (size_t)(n0 + (i0 >> 2)) * ldb + k0 + (i0 & 3) * 8, (char*)lsB + i0 * 16);
    async16(Bm + (size_t)(n0 + (i1 >> 2)) * ldb + k0 + (i1 & 3) * 8, (char*)lsB + i1 * 16);
    __syncthreads();
    short8 af[4], bfr[4];
#pragma unroll
    for (int mi = 0; mi < 4; ++mi)
      af[mi] = *(const short8*)&lsA[(wm + mi * 16 + fr) * 32 + fk];
#pragma unroll
    for (int ni = 0; ni < 4; ++ni)
      bfr[ni] = *(const short8*)&lsB[(wn + ni * 16 + fr) * 32 + fk];
#pragma unroll
    for (int mi = 0; mi < 4; ++mi)
#pragma unroll
      for (int ni = 0; ni < 4; ++ni)
        acc[mi][ni] = __builtin_amdgcn_mfma_f32_16x16x32_bf16(af[mi], bfr[ni], acc[mi][ni], 0, 0, 0);
    __syncthreads();
  }
#pragma unroll
  for (int mi = 0; mi < 4; ++mi)
#pragma unroll
    for (int ni = 0; ni < 4; ++ni)
#pragma unroll
      for (int r = 0; r < 4; ++r) {
        int gr = m0 + wm + mi * 16 + (lane >> 4) * 4 + r;
        int gc = n0 + wn + ni * 16 + fr;
        float v = acc[mi][ni][r];
        if (EPI == EPI_BF16) ((unsigned short*)Cb)[(size_t)gr * ldc + gc] = f2b(v);
        else                 ((float*)Cb)[(size_t)gr * ldc + gc] = v;
      }
}

// ---------------- fused position attention (round-5 known-good) ----------------
// per block: 128 Q-rows x 256 out-cols; K-tiles of 128 over m.
// E^T = mfma(K,Q) -> __expf -> P (bf16, swizzled LDS) + running rowsum -> P@V^T
// epilogue: sT = bf16(gpa*acc/l + gca*caT + 2x)
// VGPR=100, no spill. Do NOT hoist Q/K to registers: demand >128 spills
// (rounds 7-9: allocator pegs 128 VGPRs regardless of launch_bounds /
// amdgpu_waves_per_eu; ~50MB/dispatch scratch traffic, 183us vs 128us).
#define QR 128
#define CC 256
#define KT 128

__global__ __launch_bounds__(512, 2)
void fused_pa_k(const unsigned short* __restrict__ qkT,   // [B][N][128] (q|k)
                const unsigned short* __restrict__ vmat,  // [B][C][N]
                const unsigned short* __restrict__ caT,   // [B][N][C]
                const unsigned short* __restrict__ xnc,   // [B][N][C]
                const float* __restrict__ gpa_p, const float* __restrict__ gca_p,
                unsigned short* __restrict__ sT) {        // [B][N][C]
  __shared__ unsigned short lsQ[QR * 64];
  __shared__ unsigned short lsK[2][KT * 64];
  __shared__ unsigned short lsV[CC * KT];
  __shared__ unsigned short lsP[QR * KT];
  __shared__ float lsL[8][QR];
  __shared__ float invL[QR];

  const int bid = blockIdx.x;
  const int combo = bid & 7;                 // b*2+chalf -> same XCD shares V-half
  const int b = combo >> 1, chalf = combo & 1;
  const int qt = bid >> 3;
  const int n0 = qt * QR, c0 = chalf * CC;

  const int tid = threadIdx.x, lane = tid & 63, w = tid >> 6;
  const int fr = lane & 15, fq = lane >> 4;  // fragment row / k-quarter
  const int wr = w >> 2, wc = w & 3;         // wave out-tile 64x64

  const unsigned short* qk_b = qkT + (size_t)b * N_ * 128;
  const unsigned short* v_b  = vmat + (size_t)b * C_ * N_;

  f32x4 acc[4][4];
#pragma unroll
  for (int i = 0; i < 4; ++i)
#pragma unroll
    for (int j = 0; j < 4; ++j) acc[i][j] = (f32x4){0.f, 0.f, 0.f, 0.f};
  float lsum[8];
#pragma unroll
  for (int f = 0; f < 8; ++f) lsum[f] = 0.f;

  // stage Q (once) and K[0]
#pragma unroll
  for (int j = 0; j < 2; ++j) {
    int idx = j * 512 + tid;
    int r = idx >> 3, g = idx & 7;
    async16(qk_b + (size_t)(n0 + r) * 128 + ((g ^ (r & 7)) << 3), (char*)lsQ + idx * 16);
  }
#pragma unroll
  for (int j = 0; j < 2; ++j) {
    int idx = j * 512 + tid;
    int r = idx >> 3, g = idx & 7;
    async16(qk_b + (size_t)r * 128 + 64 + ((g ^ (r & 7)) << 3), (char*)lsK[0] + idx * 16);
  }
  __syncthreads();

  for (int it = 0; it < N_ / KT; ++it) {
    const int m0 = it * KT;
    // stage V[it]
#pragma unroll
    for (int j = 0; j < 8; ++j) {
      int idx = j * 512 + tid;
      int c = idx >> 4, g = idx & 15;
      async16(v_b + (size_t)(c0 + c) * N_ + m0 + ((g ^ (c & 7)) << 3), (char*)lsV + idx * 16);
    }
    // stage K[it+1]
    if (it < N_ / KT - 1) {
      unsigned short* dst = lsK[(it + 1) & 1];
#pragma unroll
      for (int j = 0; j < 2; ++j) {
        int idx = j * 512 + tid;
        int r = idx >> 3, g = idx & 7;
        async16(qk_b + (size_t)(m0 + KT + r) * 128 + 64 + ((g ^ (r & 7)) << 3),
                (char*)dst + idx * 16);
      }
    }
    // E^T = K . Q^T over k=64; wave w owns m-slice [w*16, w*16+16)
    const unsigned short* lk = lsK[it & 1];
    const int ms = w * 16;
    short8 afk[2];
#pragma unroll
    for (int kk = 0; kk < 2; ++kk)
      afk[kk] = *(const short8*)&lk[(ms + fr) * 64 + (((kk * 4 + fq) ^ (fr & 7)) << 3)];
#pragma unroll
    for (int f = 0; f < 8; ++f) {
      f32x4 e = (f32x4){0.f, 0.f, 0.f, 0.f};
#pragma unroll
      for (int kk = 0; kk < 2; ++kk) {
        short8 bq = *(const short8*)&lsQ[(f * 16 + fr) * 64 + (((kk * 4 + fq) ^ (fr & 7)) << 3)];
        e = __builtin_amdgcn_mfma_f32_16x16x32_bf16(afk[kk], bq, e, 0, 0, 0);
      }
      float p0 = __expf(e[0]), p1 = __expf(e[1]), p2 = __expf(e[2]), p3 = __expf(e[3]);
      float part = (p0 + p1) + (p2 + p3);
      part += __shfl_xor(part, 16, 64);
      part += __shfl_xor(part, 32, 64);
      lsum[f] += part;
      int n = f * 16 + fr;                     // P row
      int mb = ms + fq * 4;                    // 4 consecutive m
      us4_t pk = { f2b(p0), f2b(p1), f2b(p2), f2b(p3) };
      *(us4_t*)((char*)lsP + n * 256 + ((((mb >> 3) ^ (n & 7)) << 3) + (mb & 7)) * 2) = pk;
    }
    __syncthreads();   // P visible; V (and next K) landed
    // PV: out[n][c] += P[n][m] * V[c][m]
#pragma unroll
    for (int kk4 = 0; kk4 < 4; ++kk4) {
      short8 pa[4], vbf[4];
#pragma unroll
      for (int mi = 0; mi < 4; ++mi) {
        int n = wr * 64 + mi * 16 + fr;
        pa[mi] = *(const short8*)((const char*)lsP + n * 256 + (((kk4 * 4 + fq) ^ (n & 7)) << 4));
      }
#pragma unroll
      for (int ni = 0; ni < 4; ++ni) {
        int c = wc * 64 + ni * 16 + fr;
        vbf[ni] = *(const short8*)((const char*)lsV + c * 256 + (((kk4 * 4 + fq) ^ (c & 7)) << 4));
      }
#pragma unroll
      for (int mi = 0; mi < 4; ++mi)
#pragma unroll
        for (int ni = 0; ni < 4; ++ni)
          acc[mi][ni] = __builtin_amdgcn_mfma_f32_16x16x32_bf16(pa[mi], vbf[ni], acc[mi][ni], 0, 0, 0);
    }
    __syncthreads();   // all reads of lsP/lsV done before next stage/overwrite
  }

  // reduce rowsums across waves -> 1/l
  if (lane < 16) {
#pragma unroll
    for (int f = 0; f < 8; ++f) lsL[w][f * 16 + lane] = lsum[f];
  }
  __syncthreads();
  if (tid < QR) {
    float s = 0.f;
#pragma unroll
    for (int ww = 0; ww < 8; ++ww) s += lsL[ww][tid];
    invL[tid] = 1.f / s;
  }
  __syncthreads();

  const float gpa = gpa_p[0], gca = gca_p[0];
#pragma unroll
  for (int mi = 0; mi < 4; ++mi)
#pragma unroll
    for (int ni = 0; ni < 4; ++ni)
#pragma unroll
      for (int r = 0; r < 4; ++r) {
        int nl = wr * 64 + mi * 16 + fq * 4 + r;
        int gn = n0 + nl;
        int gc = c0 + wc * 64 + ni * 16 + fr;
        size_t eo = ((size_t)b * N_ + gn) * C_ + gc;
        float sv = gpa * acc[mi][ni][r] * invL[nl] + gca * b2f(caT[eo]) + 2.f * b2f(xnc[eo]);
        sT[eo] = f2b(sv);
      }
}

// ---------------- channel-attention softmax over ce partials ----------------
__global__ __launch_bounds__(256) void ce_softmax_k(const float* __restrict__ cepart,
                                                    unsigned short* __restrict__ cattn) {
  int wid = threadIdx.x >> 6, lane = threadIdx.x & 63;
  size_t row = (size_t)blockIdx.x * 4 + wid;
  float v[8]; float mn = 3.4e38f;
#pragma unroll
  for (int i = 0; i < 8; ++i) {
    size_t idx = row * C_ + (size_t)(i * 64 + lane);
    float t = cepart[idx] + cepart[idx + 1048576] + cepart[idx + 2097152] + cepart[idx + 3145728];
    v[i] = t; mn = fminf(mn, t);
  }
#pragma unroll
  for (int o = 1; o < 64; o <<= 1) mn = fminf(mn, __shfl_xor(mn, o, 64));
  float s = 0.f, p[8];
#pragma unroll
  for (int i = 0; i < 8; ++i) { p[i] = expf(mn - v[i]); s += p[i]; }
#pragma unroll
  for (int o = 1; o < 64; o <<= 1) s += __shfl_xor(s, o, 64);
  float inv = 1.f / s;
  unsigned short* orow = cattn + row * C_;
#pragma unroll
  for (int i = 0; i < 8; ++i) orow[i * 64 + lane] = f2b(p[i] * inv);
}

// ---------------- BN statistics (two stage, deterministic; yT is bf16) ----------------
__global__ __launch_bounds__(256) void bn_part_k(const unsigned short* __restrict__ yT,
                                                 float* __restrict__ part) {
  int p = blockIdx.x, t = threadIdx.x;
  const unsigned short* base = yT + (size_t)p * 256 * C_;
  float s0 = 0, q0 = 0, s1 = 0, q1 = 0;
  for (int r = 0; r < 256; ++r) {
    float a = b2f(base[(size_t)r * C_ + t]);
    float b = b2f(base[(size_t)r * C_ + t + 256]);
    s0 += a; q0 += a * a; s1 += b; q1 += b * b;
  }
  float* pp = part + (size_t)p * 1024;
  pp[t] = s0; pp[t + 256] = s1; pp[t + 512] = q0; pp[t + 768] = q1;
}

__global__ __launch_bounds__(256) void bn_final_k(const float* __restrict__ part,
                                                  const float* __restrict__ bns,
                                                  const float* __restrict__ bnb,
                                                  float* __restrict__ ab) {
  int t = threadIdx.x;
#pragma unroll
  for (int cc = 0; cc < 2; ++cc) {
    int c = t + cc * 256;
    float s = 0, q = 0;
    for (int p = 0; p < 64; ++p) { s += part[p * 1024 + c]; q += part[p * 1024 + 512 + c]; }
    float mean = s * (1.f / 16384.f);
    float var  = q * (1.f / 16384.f) - mean * mean;
    float istd = rsqrtf(var + BN_EPS);
    float a = bns[c] * istd;
    float b = bnb[c] - mean * a;
    ab[c * 2] = a; ab[c * 2 + 1] = b;
  }
}

__global__ __launch_bounds__(256) void bn_apply_k(const unsigned short* __restrict__ yT,
                                                  const float* __restrict__ ab,
                                                  float* __restrict__ out) {
  __shared__ float tile[64][65];
  int n0 = blockIdx.x * 64, o0 = blockIdx.y * 64, b = blockIdx.z;
  const unsigned short* yb = yT + ((size_t)b * N_ + n0) * C_ + o0;
#pragma unroll
  for (int j = 0; j < 16; ++j) {
    int lin = j * 256 + threadIdx.x;
    int rr = lin >> 6, cc = lin & 63;
    float v = b2f(yb[(size_t)rr * C_ + cc]);
    float a = ab[(o0 + cc) * 2], bb = ab[(o0 + cc) * 2 + 1];
    tile[cc][rr] = fmaxf(v * a + bb, 0.f);
  }
  __syncthreads();
  float* ob = out + ((size_t)b * C_ + o0) * N_ + n0;
#pragma unroll
  for (int j = 0; j < 16; ++j) {
    int lin = j * 256 + threadIdx.x;
    int rr = lin >> 6, cc = lin & 63;
    ob[(size_t)rr * N_ + cc] = tile[rr][cc];
  }
}

// ---------------- host launch ----------------

extern "C" void kernel_launch(void* const* d_in, const int* in_sizes, int n_in,
                              void* d_out, int out_size, void* d_ws, size_t ws_size,
                              hipStream_t stream) {
  (void)in_sizes; (void)n_in; (void)out_size; (void)ws_size;
  const float* x   = (const float*)d_in[0];
  const float* wq  = (const float*)d_in[1];
  const float* wk  = (const float*)d_in[2];
  const float* wv  = (const float*)d_in[3];
  const float* wf  = (const float*)d_in[4];
  const float* gpa = (const float*)d_in[5];
  const float* gca = (const float*)d_in[6];
  const float* bns = (const float*)d_in[7];
  const float* bnb = (const float*)d_in[8];
  float* out = (float*)d_out;

  char* ws = (char*)d_ws;
  size_t off = 0;
  auto carve = [&](size_t bytes) -> char* {
    off = (off + 255) & ~(size_t)255;
    char* p = ws + off; off += bytes; return p;
  };

  unsigned short* xcn   = (unsigned short*)carve((size_t)B_ * C_ * N_ * 2);  // reused as sT
  unsigned short* xnc   = (unsigned short*)carve((size_t)B_ * C_ * N_ * 2);
  unsigned short* wqkb  = (unsigned short*)carve(128 * 512 * 2);
  unsigned short* wvb   = (unsigned short*)carve(512 * 512 * 2);
  unsigned short* wfb   = (unsigned short*)carve(512 * 512 * 2);
  unsigned short* qkT   = (unsigned short*)carve((size_t)B_ * N_ * 128 * 2);
  unsigned short* vmat  = (unsigned short*)carve((size_t)B_ * C_ * N_ * 2);
  float*          cepart= (float*)carve((size_t)4 * B_ * 512 * 512 * 4);     // reused as yT (bf16)
  unsigned short* cattn = (unsigned short*)carve((size_t)B_ * 512 * 512 * 2);
  unsigned short* caT   = (unsigned short*)carve((size_t)B_ * N_ * C_ * 2);
  float*          bnpart= (float*)carve((size_t)64 * 1024 * 4);
  float*          abv   = (float*)carve(512 * 2 * 4);

  unsigned short* yT = (unsigned short*)cepart;  // overlay: cepart dead after ce_softmax
  unsigned short* sT = xcn;                      // overlay: xcn dead after ce GEMM

  // 1) conversions
  convert_x_k<<<dim3(C_ / 64, N_ / 64, B_), 256, 0, stream>>>(x, xcn, xnc);
  convert_w_k<<<dim3(1024), 256, 0, stream>>>(wq, wk, wv, wf, wqkb, wvb, wfb);

  // 2) qkT[n][0:128] = xnc @ wqk^T
  gemm_bt<EPI_BF16><<<dim3(32, 1, 4), 256, 0, stream>>>(
      xnc, 512, (size_t)N_ * C_, wqkb, 512, 0,
      qkT, 128, (size_t)N_ * 128 * 2, 512);

  // 3) v[c][m] = wv @ x
  gemm_bt<EPI_BF16><<<dim3(4, 32, 4), 256, 0, stream>>>(
      wvb, 512, 0, xnc, 512, (size_t)N_ * C_,
      vmat, N_, (size_t)C_ * N_ * 2, 512);

  // 4) ce partials = X X^T (split-K x4)
  gemm_bt<EPI_F32, true><<<dim3(4, 4, 16), 256, 0, stream>>>(
      xcn, N_, (size_t)C_ * N_, xcn, N_, (size_t)C_ * N_,
      cepart, 512, (size_t)512 * 512 * 4, 1024);

  // 5) channel softmax -> cattn bf16
  ce_softmax_k<<<dim3(B_ * 512 / 4), 256, 0, stream>>>(cepart, cattn);

  // 6) caT[n][c] = xnc @ cattn^T
  gemm_bt<EPI_BF16><<<dim3(32, 4, 4), 256, 0, stream>>>(
      xnc, 512, (size_t)N_ * C_, cattn, 512, (size_t)512 * 512,
      caT, 512, (size_t)N_ * C_ * 2, 512);

  // 7) fused position attention + combine epilogue -> sT
  fused_pa_k<<<dim3(256), 512, 0, stream>>>(qkT, vmat, caT, xnc, gpa, gca, sT);

  // 8) yT[n][o] = sT @ wfuse^T (bf16 out; BN stats tolerate bf16 rounding)
  gemm_bt<EPI_BF16><<<dim3(32, 4, 4), 256, 0, stream>>>(
      sT, 512, (size_t)N_ * C_, wfb, 512, 0,
      yT, 512, (size_t)N_ * C_ * 2, 512);

  // 9) BN stats + apply + transpose + relu
  bn_part_k<<<dim3(64), 256, 0, stream>>>(yT, bnpart);
  bn_final_k<<<dim3(1), 256, 0, stream>>>(bnpart, bns, bnb, abv);
  bn_apply_k<<<dim3(N_ / 64, C_ / 64, B_), 256, 0, stream>>>(yT, abv, out);
}

// Round 11
// 242.369 us; speedup vs baseline: 1.3206x; 1.0629x over previous
//
#include <hip/hip_runtime.h>
#include <cstdint>
#include <cstddef>

#define B_   4
#define C_   512
#define N_   4096
#define BN_EPS 1e-5f

typedef __attribute__((ext_vector_type(8))) short short8;
typedef __attribute__((ext_vector_type(8))) unsigned short ushort8;
typedef __attribute__((ext_vector_type(4))) unsigned short us4_t;
typedef __attribute__((ext_vector_type(4))) float f32x4;

__device__ __forceinline__ unsigned short f2b(float f) {
  union { float f; unsigned u; } v; v.f = f;
  unsigned u = v.u;
  return (unsigned short)((u + 0x7fffu + ((u >> 16) & 1u)) >> 16);
}
__device__ __forceinline__ float b2f(unsigned short h) {
  union { unsigned u; float f; } v; v.u = ((unsigned)h) << 16;
  return v.f;
}
__device__ __forceinline__ void async16(const void* g, void* l) {
  __builtin_amdgcn_global_load_lds((const __attribute__((address_space(1))) void*)g,
                                   (__attribute__((address_space(3))) void*)l, 16, 0, 0);
}

// ---------------- conversion kernel (x + weights, one launch) ----------------
// grid (8, 64, 5): z<4 -> x-tile transpose/convert for batch z; z==4 -> weights.

__global__ __launch_bounds__(256) void convert_x_k(const float* __restrict__ x,
                                                   unsigned short* __restrict__ xcn,
                                                   unsigned short* __restrict__ xnc,
                                                   const float* __restrict__ wq,
                                                   const float* __restrict__ wk,
                                                   const float* __restrict__ wv,
                                                   const float* __restrict__ wf,
                                                   unsigned short* __restrict__ wqk,
                                                   unsigned short* __restrict__ wvb,
                                                   unsigned short* __restrict__ wfb) {
  __shared__ float tile[64][65];
  int bz = blockIdx.z;
  if (bz == 4) {                       // weight conversion: 512 blocks x 256 thr x 2 elems
    int lin = (blockIdx.y * 8 + blockIdx.x) * 256 + threadIdx.x;   // 0..131071
    wvb[lin] = f2b(wv[lin]);  wvb[lin + 131072] = f2b(wv[lin + 131072]);
    wfb[lin] = f2b(wf[lin]);  wfb[lin + 131072] = f2b(wf[lin + 131072]);
    if (lin < 65536) {
      int row = lin >> 9, col = lin & 511;
      float v = (row < 64) ? wq[row * 512 + col] : wk[(row - 64) * 512 + col];
      wqk[lin] = f2b(v);
    }
    return;
  }
  int c0 = blockIdx.x * 64, n0 = blockIdx.y * 64, b = bz;
  const float* xb = x + ((size_t)b * C_ + c0) * N_ + n0;
  unsigned short* cn = xcn + ((size_t)b * C_ + c0) * N_ + n0;
#pragma unroll
  for (int j = 0; j < 16; ++j) {
    int lin = j * 256 + threadIdx.x;
    int rr = lin >> 6, cc = lin & 63;
    float v = xb[(size_t)rr * N_ + cc];
    cn[(size_t)rr * N_ + cc] = f2b(v);
    tile[cc][rr] = v;
  }
  __syncthreads();
  unsigned short* nc = xnc + ((size_t)b * N_ + n0) * C_ + c0;
#pragma unroll
  for (int j = 0; j < 16; ++j) {
    int lin = j * 256 + threadIdx.x;
    int rr = lin >> 6, cc = lin & 63;
    nc[(size_t)rr * C_ + cc] = f2b(tile[rr][cc]);
  }
}

// ---------------- generic MFMA GEMM:  C[m,n] = sum_k A[m,k] * B'[n,k] ----------------
// EPI_YB: bf16 C-write + per-block column {sum, sumsq} partials -> part[rg*1024 + col*2]

enum { EPI_BF16 = 0, EPI_F32 = 1, EPI_YB = 2 };

template<int EPI, bool SPLITK = false>
__global__ __launch_bounds__(256)
void gemm_bt(const unsigned short* __restrict__ A, size_t lda, size_t sA,
             const unsigned short* __restrict__ Bm, size_t ldb, size_t sB,
             void* __restrict__ Cv, size_t ldc, size_t sCbytes, int K,
             float* __restrict__ part) {
  const int bz = blockIdx.z;
  const int m0 = blockIdx.x * 128, n0 = blockIdx.y * 128;
  char* Cb;
  if (SPLITK) {
    int bidx = bz & 3, ch = bz >> 2;
    A  += (size_t)bidx * sA + (size_t)ch * (size_t)K;
    Bm += (size_t)bidx * sB + (size_t)ch * (size_t)K;
    Cb = (char*)Cv + (size_t)bidx * sCbytes + (size_t)ch * 4u * sCbytes;
  } else {
    A  += (size_t)bz * sA;
    Bm += (size_t)bz * sB;
    Cb = (char*)Cv + (size_t)bz * sCbytes;
  }
  __shared__ unsigned short lsA[128 * 32];
  __shared__ unsigned short lsB[128 * 32];
  const int tid = threadIdx.x, lane = tid & 63, w = tid >> 6;
  const int wm = (w >> 1) * 64, wn = (w & 1) * 64;
  const int fr = lane & 15, fk = (lane >> 4) * 8;
  f32x4 acc[4][4];
#pragma unroll
  for (int i = 0; i < 4; ++i)
#pragma unroll
    for (int j = 0; j < 4; ++j) acc[i][j] = (f32x4){0.f, 0.f, 0.f, 0.f};

  const int i0 = tid, i1 = tid + 256;
  for (int k0 = 0; k0 < K; k0 += 32) {
    async16(A  + (size_t)(m0 + (i0 >> 2)) * lda + k0 + (i0 & 3) * 8, (char*)lsA + i0 * 16);
    async16(A  + (size_t)(m0 + (i1 >> 2)) * lda + k0 + (i1 & 3) * 8, (char*)lsA + i1 * 16);
    async16(Bm + (size_t)(n0 + (i0 >> 2)) * ldb + k0 + (i0 & 3) * 8, (char*)lsB + i0 * 16);
    async16(Bm + (size_t)(n0 + (i1 >> 2)) * ldb + k0 + (i1 & 3) * 8, (char*)lsB + i1 * 16);
    __syncthreads();
    short8 af[4], bfr[4];
#pragma unroll
    for (int mi = 0; mi < 4; ++mi)
      af[mi] = *(const short8*)&lsA[(wm + mi * 16 + fr) * 32 + fk];
#pragma unroll
    for (int ni = 0; ni < 4; ++ni)
      bfr[ni] = *(const short8*)&lsB[(wn + ni * 16 + fr) * 32 + fk];
#pragma unroll
    for (int mi = 0; mi < 4; ++mi)
#pragma unroll
      for (int ni = 0; ni < 4; ++ni)
        acc[mi][ni] = __builtin_amdgcn_mfma_f32_16x16x32_bf16(af[mi], bfr[ni], acc[mi][ni], 0, 0, 0);
    __syncthreads();
  }
  float cs[4] = {0.f, 0.f, 0.f, 0.f}, cq[4] = {0.f, 0.f, 0.f, 0.f};
#pragma unroll
  for (int mi = 0; mi < 4; ++mi)
#pragma unroll
    for (int ni = 0; ni < 4; ++ni)
#pragma unroll
      for (int r = 0; r < 4; ++r) {
        int gr = m0 + wm + mi * 16 + (lane >> 4) * 4 + r;
        int gc = n0 + wn + ni * 16 + fr;
        float v = acc[mi][ni][r];
        if (EPI == EPI_F32) ((float*)Cb)[(size_t)gr * ldc + gc] = v;
        else                ((unsigned short*)Cb)[(size_t)gr * ldc + gc] = f2b(v);
        if (EPI == EPI_YB) { cs[ni] += v; cq[ni] += v * v; }
      }
  if (EPI == EPI_YB) {
    // reduce over the 4 fq lane-groups (rows), leave per-column partials on fr lanes
#pragma unroll
    for (int ni = 0; ni < 4; ++ni) {
      cs[ni] += __shfl_xor(cs[ni], 16, 64); cs[ni] += __shfl_xor(cs[ni], 32, 64);
      cq[ni] += __shfl_xor(cq[ni], 16, 64); cq[ni] += __shfl_xor(cq[ni], 32, 64);
    }
    float* fb = (float*)lsA;                 // [2 wm][128 col][2] = 2KB, lsA reuse (post-barrier)
    if (lane < 16) {
#pragma unroll
      for (int ni = 0; ni < 4; ++ni) {
        int col = wn + ni * 16 + lane;
        fb[((w >> 1) * 128 + col) * 2]     = cs[ni];
        fb[((w >> 1) * 128 + col) * 2 + 1] = cq[ni];
      }
    }
    __syncthreads();
    if (tid < 128) {
      float s = fb[tid * 2] + fb[(128 + tid) * 2];
      float q = fb[tid * 2 + 1] + fb[(128 + tid) * 2 + 1];
      int rg = bz * 32 + blockIdx.x;                 // row-group 0..127
      int gcol = blockIdx.y * 128 + tid;
      part[(size_t)rg * 1024 + gcol * 2]     = s;
      part[(size_t)rg * 1024 + gcol * 2 + 1] = q;
    }
  }
}

// ---------------- fused position attention (r5 base + E 4m x 2n split) ----------------
// per block: 128 Q-rows x 256 out-cols; K-tiles of 128 over m.
// E-phase: wave = 32m x 64n (was 16m x 128n): Q-LDS-read halves (128->64 KB/iter),
// K-read doubles (16->32) -> net -48 KB/iter on the LDS pipe (the bottleneck).
// Stage/PV/epilogue byte-identical to the verified round-5 kernel. VGPR stays ~100.
#define QR 128
#define CC 256
#define KT 128

__global__ __launch_bounds__(512, 2)
void fused_pa_k(const unsigned short* __restrict__ qkT,   // [B][N][128] (q|k)
                const unsigned short* __restrict__ vmat,  // [B][C][N]
                const unsigned short* __restrict__ caT,   // [B][N][C]
                const unsigned short* __restrict__ xnc,   // [B][N][C]
                const float* __restrict__ gpa_p, const float* __restrict__ gca_p,
                unsigned short* __restrict__ sT) {        // [B][N][C]
  __shared__ unsigned short lsQ[QR * 64];
  __shared__ unsigned short lsK[2][KT * 64];
  __shared__ unsigned short lsV[CC * KT];
  __shared__ unsigned short lsP[QR * KT];
  __shared__ float lsL[8][64];
  __shared__ float invL[QR];

  const int bid = blockIdx.x;
  const int combo = bid & 7;                 // b*2+chalf -> same XCD shares V-half
  const int b = combo >> 1, chalf = combo & 1;
  const int qt = bid >> 3;
  const int n0 = qt * QR, c0 = chalf * CC;

  const int tid = threadIdx.x, lane = tid & 63, w = tid >> 6;
  const int fr = lane & 15, fq = lane >> 4;  // fragment row / k-quarter
  const int wr = w >> 2, wc = w & 3;         // PV wave out-tile 64x64
  const int ms = (w & 3) * 32;               // E-phase m-slice (32 rows)
  const int nb = (w >> 2) * 64;              // E-phase n-half (64 cols)

  const unsigned short* qk_b = qkT + (size_t)b * N_ * 128;
  const unsigned short* v_b  = vmat + (size_t)b * C_ * N_;

  f32x4 acc[4][4];
#pragma unroll
  for (int i = 0; i < 4; ++i)
#pragma unroll
    for (int j = 0; j < 4; ++j) acc[i][j] = (f32x4){0.f, 0.f, 0.f, 0.f};
  float lsum[4] = {0.f, 0.f, 0.f, 0.f};

  // stage Q (once) and K[0]
#pragma unroll
  for (int j = 0; j < 2; ++j) {
    int idx = j * 512 + tid;
    int r = idx >> 3, g = idx & 7;
    async16(qk_b + (size_t)(n0 + r) * 128 + ((g ^ (r & 7)) << 3), (char*)lsQ + idx * 16);
  }
#pragma unroll
  for (int j = 0; j < 2; ++j) {
    int idx = j * 512 + tid;
    int r = idx >> 3, g = idx & 7;
    async16(qk_b + (size_t)r * 128 + 64 + ((g ^ (r & 7)) << 3), (char*)lsK[0] + idx * 16);
  }
  __syncthreads();

  for (int it = 0; it < N_ / KT; ++it) {
    const int m0 = it * KT;
    // stage V[it]
#pragma unroll
    for (int j = 0; j < 8; ++j) {
      int idx = j * 512 + tid;
      int c = idx >> 4, g = idx & 15;
      async16(v_b + (size_t)(c0 + c) * N_ + m0 + ((g ^ (c & 7)) << 3), (char*)lsV + idx * 16);
    }
    // stage K[it+1]
    if (it < N_ / KT - 1) {
      unsigned short* dst = lsK[(it + 1) & 1];
#pragma unroll
      for (int j = 0; j < 2; ++j) {
        int idx = j * 512 + tid;
        int r = idx >> 3, g = idx & 7;
        async16(qk_b + (size_t)(m0 + KT + r) * 128 + 64 + ((g ^ (r & 7)) << 3),
                (char*)dst + idx * 16);
      }
    }
    // E^T = K . Q^T over k=64; wave owns 32m x 64n
    const unsigned short* lk = lsK[it & 1];
    short8 afk[2][2];
#pragma unroll
    for (int mi = 0; mi < 2; ++mi)
#pragma unroll
      for (int kk = 0; kk < 2; ++kk)
        afk[mi][kk] = *(const short8*)&lk[(ms + mi * 16 + fr) * 64 + (((kk * 4 + fq) ^ (fr & 7)) << 3)];
#pragma unroll
    for (int f = 0; f < 4; ++f) {
      int n = nb + f * 16 + fr;                // P row
      short8 bq0 = *(const short8*)&lsQ[n * 64 + (((0 * 4 + fq) ^ (fr & 7)) << 3)];
      short8 bq1 = *(const short8*)&lsQ[n * 64 + (((1 * 4 + fq) ^ (fr & 7)) << 3)];
      float part = 0.f;
#pragma unroll
      for (int mi = 0; mi < 2; ++mi) {
        f32x4 e = (f32x4){0.f, 0.f, 0.f, 0.f};
        e = __builtin_amdgcn_mfma_f32_16x16x32_bf16(afk[mi][0], bq0, e, 0, 0, 0);
        e = __builtin_amdgcn_mfma_f32_16x16x32_bf16(afk[mi][1], bq1, e, 0, 0, 0);
        float p0 = __expf(e[0]), p1 = __expf(e[1]), p2 = __expf(e[2]), p3 = __expf(e[3]);
        part += (p0 + p1) + (p2 + p3);
        int mb = ms + mi * 16 + fq * 4;        // 4 consecutive m
        us4_t pk = { f2b(p0), f2b(p1), f2b(p2), f2b(p3) };
        *(us4_t*)((char*)lsP + n * 256 + ((((mb >> 3) ^ (n & 7)) << 3) + (mb & 7)) * 2) = pk;
      }
      part += __shfl_xor(part, 16, 64);
      part += __shfl_xor(part, 32, 64);
      lsum[f] += part;
    }
    __syncthreads();   // P visible; V (and next K) landed
    // PV: out[n][c] += P[n][m] * V[c][m]
#pragma unroll
    for (int kk4 = 0; kk4 < 4; ++kk4) {
      short8 pa[4], vbf[4];
#pragma unroll
      for (int mi = 0; mi < 4; ++mi) {
        int n = wr * 64 + mi * 16 + fr;
        pa[mi] = *(const short8*)((const char*)lsP + n * 256 + (((kk4 * 4 + fq) ^ (n & 7)) << 4));
      }
#pragma unroll
      for (int ni = 0; ni < 4; ++ni) {
        int c = wc * 64 + ni * 16 + fr;
        vbf[ni] = *(const short8*)((const char*)lsV + c * 256 + (((kk4 * 4 + fq) ^ (c & 7)) << 4));
      }
#pragma unroll
      for (int mi = 0; mi < 4; ++mi)
#pragma unroll
        for (int ni = 0; ni < 4; ++ni)
          acc[mi][ni] = __builtin_amdgcn_mfma_f32_16x16x32_bf16(pa[mi], vbf[ni], acc[mi][ni], 0, 0, 0);
    }
    __syncthreads();   // all reads of lsP/lsV done before next stage/overwrite
  }

  // reduce rowsums: row n = nh*64 + j summed over 4 m-slice waves (w = nh*4 + ma)
  if (lane < 16) {
#pragma unroll
    for (int f = 0; f < 4; ++f) lsL[w][f * 16 + lane] = lsum[f];
  }
  __syncthreads();
  if (tid < QR) {
    int nh = tid >> 6, j = tid & 63;
    invL[tid] = 1.f / (lsL[4 * nh][j] + lsL[4 * nh + 1][j] + lsL[4 * nh + 2][j] + lsL[4 * nh + 3][j]);
  }
  __syncthreads();

  const float gpa = gpa_p[0], gca = gca_p[0];
#pragma unroll
  for (int mi = 0; mi < 4; ++mi)
#pragma unroll
    for (int ni = 0; ni < 4; ++ni)
#pragma unroll
      for (int r = 0; r < 4; ++r) {
        int nl = wr * 64 + mi * 16 + fq * 4 + r;
        int gn = n0 + nl;
        int gc = c0 + wc * 64 + ni * 16 + fr;
        size_t eo = ((size_t)b * N_ + gn) * C_ + gc;
        float sv = gpa * acc[mi][ni][r] * invL[nl] + gca * b2f(caT[eo]) + 2.f * b2f(xnc[eo]);
        sT[eo] = f2b(sv);
      }
}

// ---------------- channel-attention softmax over ce partials ----------------
__global__ __launch_bounds__(256) void ce_softmax_k(const float* __restrict__ cepart,
                                                    unsigned short* __restrict__ cattn) {
  int wid = threadIdx.x >> 6, lane = threadIdx.x & 63;
  size_t row = (size_t)blockIdx.x * 4 + wid;
  float v[8]; float mn = 3.4e38f;
#pragma unroll
  for (int i = 0; i < 8; ++i) {
    size_t idx = row * C_ + (size_t)(i * 64 + lane);
    float t = cepart[idx] + cepart[idx + 1048576] + cepart[idx + 2097152] + cepart[idx + 3145728];
    v[i] = t; mn = fminf(mn, t);
  }
#pragma unroll
  for (int o = 1; o < 64; o <<= 1) mn = fminf(mn, __shfl_xor(mn, o, 64));
  float s = 0.f, p[8];
#pragma unroll
  for (int i = 0; i < 8; ++i) { p[i] = expf(mn - v[i]); s += p[i]; }
#pragma unroll
  for (int o = 1; o < 64; o <<= 1) s += __shfl_xor(s, o, 64);
  float inv = 1.f / s;
  unsigned short* orow = cattn + row * C_;
#pragma unroll
  for (int i = 0; i < 8; ++i) orow[i * 64 + lane] = f2b(p[i] * inv);
}

// ---------------- BN final (reduce 128 row-group partials) + apply ----------------
__global__ __launch_bounds__(256) void bn_final_k(const float* __restrict__ part,
                                                  const float* __restrict__ bns,
                                                  const float* __restrict__ bnb,
                                                  float* __restrict__ ab) {
  int t = threadIdx.x;
#pragma unroll
  for (int cc = 0; cc < 2; ++cc) {
    int c = t + cc * 256;
    float s = 0, q = 0;
    for (int p = 0; p < 128; ++p) { s += part[(size_t)p * 1024 + c * 2]; q += part[(size_t)p * 1024 + c * 2 + 1]; }
    float mean = s * (1.f / 16384.f);
    float var  = q * (1.f / 16384.f) - mean * mean;
    float istd = rsqrtf(var + BN_EPS);
    float a = bns[c] * istd;
    float b = bnb[c] - mean * a;
    ab[c * 2] = a; ab[c * 2 + 1] = b;
  }
}

__global__ __launch_bounds__(256) void bn_apply_k(const unsigned short* __restrict__ yT,
                                                  const float* __restrict__ ab,
                                                  float* __restrict__ out) {
  __shared__ float tile[64][65];
  int n0 = blockIdx.x * 64, o0 = blockIdx.y * 64, b = blockIdx.z;
  const unsigned short* yb = yT + ((size_t)b * N_ + n0) * C_ + o0;
#pragma unroll
  for (int j = 0; j < 16; ++j) {
    int lin = j * 256 + threadIdx.x;
    int rr = lin >> 6, cc = lin & 63;
    float v = b2f(yb[(size_t)rr * C_ + cc]);
    float a = ab[(o0 + cc) * 2], bb = ab[(o0 + cc) * 2 + 1];
    tile[cc][rr] = fmaxf(v * a + bb, 0.f);
  }
  __syncthreads();
  float* ob = out + ((size_t)b * C_ + o0) * N_ + n0;
#pragma unroll
  for (int j = 0; j < 16; ++j) {
    int lin = j * 256 + threadIdx.x;
    int rr = lin >> 6, cc = lin & 63;
    ob[(size_t)rr * N_ + cc] = tile[rr][cc];
  }
}

// ---------------- host launch ----------------

extern "C" void kernel_launch(void* const* d_in, const int* in_sizes, int n_in,
                              void* d_out, int out_size, void* d_ws, size_t ws_size,
                              hipStream_t stream) {
  (void)in_sizes; (void)n_in; (void)out_size; (void)ws_size;
  const float* x   = (const float*)d_in[0];
  const float* wq  = (const float*)d_in[1];
  const float* wk  = (const float*)d_in[2];
  const float* wv  = (const float*)d_in[3];
  const float* wf  = (const float*)d_in[4];
  const float* gpa = (const float*)d_in[5];
  const float* gca = (const float*)d_in[6];
  const float* bns = (const float*)d_in[7];
  const float* bnb = (const float*)d_in[8];
  float* out = (float*)d_out;

  char* ws = (char*)d_ws;
  size_t off = 0;
  auto carve = [&](size_t bytes) -> char* {
    off = (off + 255) & ~(size_t)255;
    char* p = ws + off; off += bytes; return p;
  };

  unsigned short* xcn   = (unsigned short*)carve((size_t)B_ * C_ * N_ * 2);  // reused as sT
  unsigned short* xnc   = (unsigned short*)carve((size_t)B_ * C_ * N_ * 2);
  unsigned short* wqkb  = (unsigned short*)carve(128 * 512 * 2);
  unsigned short* wvb   = (unsigned short*)carve(512 * 512 * 2);
  unsigned short* wfb   = (unsigned short*)carve(512 * 512 * 2);
  unsigned short* qkT   = (unsigned short*)carve((size_t)B_ * N_ * 128 * 2);
  unsigned short* vmat  = (unsigned short*)carve((size_t)B_ * C_ * N_ * 2);
  float*          cepart= (float*)carve((size_t)4 * B_ * 512 * 512 * 4);     // reused as yT (bf16)
  unsigned short* cattn = (unsigned short*)carve((size_t)B_ * 512 * 512 * 2);
  unsigned short* caT   = (unsigned short*)carve((size_t)B_ * N_ * C_ * 2);
  float*          bnpart= (float*)carve((size_t)128 * 1024 * 4);
  float*          abv   = (float*)carve(512 * 2 * 4);

  unsigned short* yT = (unsigned short*)cepart;  // overlay: cepart dead after ce_softmax
  unsigned short* sT = xcn;                      // overlay: xcn dead after ce GEMM

  // 1) conversions (x + weights in one launch)
  convert_x_k<<<dim3(C_ / 64, N_ / 64, 5), 256, 0, stream>>>(
      x, xcn, xnc, wq, wk, wv, wf, wqkb, wvb, wfb);

  // 2) qkT[n][0:128] = xnc @ wqk^T
  gemm_bt<EPI_BF16><<<dim3(32, 1, 4), 256, 0, stream>>>(
      xnc, 512, (size_t)N_ * C_, wqkb, 512, 0,
      qkT, 128, (size_t)N_ * 128 * 2, 512, nullptr);

  // 3) v[c][m] = wv @ x
  gemm_bt<EPI_BF16><<<dim3(4, 32, 4), 256, 0, stream>>>(
      wvb, 512, 0, xnc, 512, (size_t)N_ * C_,
      vmat, N_, (size_t)C_ * N_ * 2, 512, nullptr);

  // 4) ce partials = X X^T (split-K x4)
  gemm_bt<EPI_F32, true><<<dim3(4, 4, 16), 256, 0, stream>>>(
      xcn, N_, (size_t)C_ * N_, xcn, N_, (size_t)C_ * N_,
      cepart, 512, (size_t)512 * 512 * 4, 1024, nullptr);

  // 5) channel softmax -> cattn bf16
  ce_softmax_k<<<dim3(B_ * 512 / 4), 256, 0, stream>>>(cepart, cattn);

  // 6) caT[n][c] = xnc @ cattn^T
  gemm_bt<EPI_BF16><<<dim3(32, 4, 4), 256, 0, stream>>>(
      xnc, 512, (size_t)N_ * C_, cattn, 512, (size_t)512 * 512,
      caT, 512, (size_t)N_ * C_ * 2, 512, nullptr);

  // 7) fused position attention + combine epilogue -> sT
  fused_pa_k<<<dim3(256), 512, 0, stream>>>(qkT, vmat, caT, xnc, gpa, gca, sT);

  // 8) yT[n][o] = sT @ wfuse^T (bf16) with fused per-block BN column partials
  gemm_bt<EPI_YB><<<dim3(32, 4, 4), 256, 0, stream>>>(
      sT, 512, (size_t)N_ * C_, wfb, 512, 0,
      yT, 512, (size_t)N_ * C_ * 2, 512, bnpart);

  // 9) BN finalize + apply + transpose + relu
  bn_final_k<<<dim3(1), 256, 0, stream>>>(bnpart, bns, bnb, abv);
  bn_apply_k<<<dim3(N_ / 64, C_ / 64, B_), 256, 0, stream>>>(yT, abv, out);
}

// Round 12
// 214.658 us; speedup vs baseline: 1.4910x; 1.1291x over previous
//
#include <hip/hip_runtime.h>
#include <cstdint>
#include <cstddef>

#define B_   4
#define C_   512
#define N_   4096
#define BN_EPS 1e-5f

typedef __attribute__((ext_vector_type(8))) short short8;
typedef __attribute__((ext_vector_type(8))) unsigned short ushort8;
typedef __attribute__((ext_vector_type(4))) unsigned short us4_t;
typedef __attribute__((ext_vector_type(4))) float f32x4;

__device__ __forceinline__ unsigned short f2b(float f) {
  union { float f; unsigned u; } v; v.f = f;
  unsigned u = v.u;
  return (unsigned short)((u + 0x7fffu + ((u >> 16) & 1u)) >> 16);
}
__device__ __forceinline__ float b2f(unsigned short h) {
  union { unsigned u; float f; } v; v.u = ((unsigned)h) << 16;
  return v.f;
}
__device__ __forceinline__ void async16(const void* g, void* l) {
  __builtin_amdgcn_global_load_lds((const __attribute__((address_space(1))) void*)g,
                                   (__attribute__((address_space(3))) void*)l, 16, 0, 0);
}

// ---------------- conversion kernel (x + weights, one launch) ----------------
// grid (8, 64, 5): z<4 -> x-tile transpose/convert for batch z; z==4 -> weights.

__global__ __launch_bounds__(256) void convert_x_k(const float* __restrict__ x,
                                                   unsigned short* __restrict__ xcn,
                                                   unsigned short* __restrict__ xnc,
                                                   const float* __restrict__ wq,
                                                   const float* __restrict__ wk,
                                                   const float* __restrict__ wv,
                                                   const float* __restrict__ wf,
                                                   unsigned short* __restrict__ wqk,
                                                   unsigned short* __restrict__ wvb,
                                                   unsigned short* __restrict__ wfb) {
  __shared__ float tile[64][65];
  int bz = blockIdx.z;
  if (bz == 4) {                       // weight conversion: 512 blocks x 256 thr x 2 elems
    int lin = (blockIdx.y * 8 + blockIdx.x) * 256 + threadIdx.x;   // 0..131071
    wvb[lin] = f2b(wv[lin]);  wvb[lin + 131072] = f2b(wv[lin + 131072]);
    wfb[lin] = f2b(wf[lin]);  wfb[lin + 131072] = f2b(wf[lin + 131072]);
    if (lin < 65536) {
      int row = lin >> 9, col = lin & 511;
      float v = (row < 64) ? wq[row * 512 + col] : wk[(row - 64) * 512 + col];
      wqk[lin] = f2b(v);
    }
    return;
  }
  int c0 = blockIdx.x * 64, n0 = blockIdx.y * 64, b = bz;
  const float* xb = x + ((size_t)b * C_ + c0) * N_ + n0;
  unsigned short* cn = xcn + ((size_t)b * C_ + c0) * N_ + n0;
#pragma unroll
  for (int j = 0; j < 16; ++j) {
    int lin = j * 256 + threadIdx.x;
    int rr = lin >> 6, cc = lin & 63;
    float v = xb[(size_t)rr * N_ + cc];
    cn[(size_t)rr * N_ + cc] = f2b(v);
    tile[cc][rr] = v;
  }
  __syncthreads();
  unsigned short* nc = xnc + ((size_t)b * N_ + n0) * C_ + c0;
#pragma unroll
  for (int j = 0; j < 16; ++j) {
    int lin = j * 256 + threadIdx.x;
    int rr = lin >> 6, cc = lin & 63;
    nc[(size_t)rr * C_ + cc] = f2b(tile[rr][cc]);
  }
}

// ---------------- generic MFMA GEMM core:  C[m,n] = sum_k A[m,k] * B'[n,k] ----------------
// EPI_YB: bf16 C-write + per-block column {sum, sumsq} partials -> part[rg*1024 + col*2]

enum { EPI_BF16 = 0, EPI_F32 = 1, EPI_YB = 2 };

template<int EPI, bool SPLITK>
__device__ __forceinline__ void gemm_core(
    const unsigned short* __restrict__ A, size_t lda, size_t sA,
    const unsigned short* __restrict__ Bm, size_t ldb, size_t sB,
    void* __restrict__ Cv, size_t ldc, size_t sCbytes, int K,
    float* __restrict__ part, int bx, int by, int bz,
    unsigned short* lsA, unsigned short* lsB) {
  const int m0 = bx * 128, n0 = by * 128;
  char* Cb;
  if (SPLITK) {
    int bidx = bz & 3, ch = bz >> 2;
    A  += (size_t)bidx * sA + (size_t)ch * (size_t)K;
    Bm += (size_t)bidx * sB + (size_t)ch * (size_t)K;
    Cb = (char*)Cv + (size_t)bidx * sCbytes + (size_t)ch * 4u * sCbytes;
  } else {
    A  += (size_t)bz * sA;
    Bm += (size_t)bz * sB;
    Cb = (char*)Cv + (size_t)bz * sCbytes;
  }
  const int tid = threadIdx.x, lane = tid & 63, w = tid >> 6;
  const int wm = (w >> 1) * 64, wn = (w & 1) * 64;
  const int fr = lane & 15, fk = (lane >> 4) * 8;
  f32x4 acc[4][4];
#pragma unroll
  for (int i = 0; i < 4; ++i)
#pragma unroll
    for (int j = 0; j < 4; ++j) acc[i][j] = (f32x4){0.f, 0.f, 0.f, 0.f};

  const int i0 = tid, i1 = tid + 256;
  for (int k0 = 0; k0 < K; k0 += 32) {
    async16(A  + (size_t)(m0 + (i0 >> 2)) * lda + k0 + (i0 & 3) * 8, (char*)lsA + i0 * 16);
    async16(A  + (size_t)(m0 + (i1 >> 2)) * lda + k0 + (i1 & 3) * 8, (char*)lsA + i1 * 16);
    async16(Bm + (size_t)(n0 + (i0 >> 2)) * ldb + k0 + (i0 & 3) * 8, (char*)lsB + i0 * 16);
    async16(Bm + (size_t)(n0 + (i1 >> 2)) * ldb + k0 + (i1 & 3) * 8, (char*)lsB + i1 * 16);
    __syncthreads();
    short8 af[4], bfr[4];
#pragma unroll
    for (int mi = 0; mi < 4; ++mi)
      af[mi] = *(const short8*)&lsA[(wm + mi * 16 + fr) * 32 + fk];
#pragma unroll
    for (int ni = 0; ni < 4; ++ni)
      bfr[ni] = *(const short8*)&lsB[(wn + ni * 16 + fr) * 32 + fk];
#pragma unroll
    for (int mi = 0; mi < 4; ++mi)
#pragma unroll
      for (int ni = 0; ni < 4; ++ni)
        acc[mi][ni] = __builtin_amdgcn_mfma_f32_16x16x32_bf16(af[mi], bfr[ni], acc[mi][ni], 0, 0, 0);
    __syncthreads();
  }
  float cs[4] = {0.f, 0.f, 0.f, 0.f}, cq[4] = {0.f, 0.f, 0.f, 0.f};
#pragma unroll
  for (int mi = 0; mi < 4; ++mi)
#pragma unroll
    for (int ni = 0; ni < 4; ++ni)
#pragma unroll
      for (int r = 0; r < 4; ++r) {
        int gr = m0 + wm + mi * 16 + (lane >> 4) * 4 + r;
        int gc = n0 + wn + ni * 16 + fr;
        float v = acc[mi][ni][r];
        if (EPI == EPI_F32) ((float*)Cb)[(size_t)gr * ldc + gc] = v;
        else                ((unsigned short*)Cb)[(size_t)gr * ldc + gc] = f2b(v);
        if (EPI == EPI_YB) { cs[ni] += v; cq[ni] += v * v; }
      }
  if (EPI == EPI_YB) {
#pragma unroll
    for (int ni = 0; ni < 4; ++ni) {
      cs[ni] += __shfl_xor(cs[ni], 16, 64); cs[ni] += __shfl_xor(cs[ni], 32, 64);
      cq[ni] += __shfl_xor(cq[ni], 16, 64); cq[ni] += __shfl_xor(cq[ni], 32, 64);
    }
    float* fb = (float*)lsA;                 // [2 wm][128 col][2] = 2KB, lsA reuse (post-barrier)
    if (lane < 16) {
#pragma unroll
      for (int ni = 0; ni < 4; ++ni) {
        int col = wn + ni * 16 + lane;
        fb[((w >> 1) * 128 + col) * 2]     = cs[ni];
        fb[((w >> 1) * 128 + col) * 2 + 1] = cq[ni];
      }
    }
    __syncthreads();
    if (tid < 128) {
      float s = fb[tid * 2] + fb[(128 + tid) * 2];
      float q = fb[tid * 2 + 1] + fb[(128 + tid) * 2 + 1];
      int rg = bz * 32 + bx;                 // row-group 0..127
      int gcol = by * 128 + tid;
      part[(size_t)rg * 1024 + gcol * 2]     = s;
      part[(size_t)rg * 1024 + gcol * 2 + 1] = q;
    }
  }
}

template<int EPI, bool SPLITK = false>
__global__ __launch_bounds__(256)
void gemm_bt(const unsigned short* __restrict__ A, size_t lda, size_t sA,
             const unsigned short* __restrict__ Bm, size_t ldb, size_t sB,
             void* __restrict__ Cv, size_t ldc, size_t sCbytes, int K,
             float* __restrict__ part) {
  __shared__ unsigned short lsA[128 * 32];
  __shared__ unsigned short lsB[128 * 32];
  gemm_core<EPI, SPLITK>(A, lda, sA, Bm, ldb, sB, Cv, ldc, sCbytes, K, part,
                         blockIdx.x, blockIdx.y, blockIdx.z, lsA, lsB);
}

// Merged independent GEMMs: ce (split-K, longest -> first), qkT, v. 896 blocks.
__global__ __launch_bounds__(256)
void gemm3_k(const unsigned short* __restrict__ xnc, const unsigned short* __restrict__ xcn,
             const unsigned short* __restrict__ wqkb, const unsigned short* __restrict__ wvb,
             unsigned short* __restrict__ qkT, unsigned short* __restrict__ vmat,
             float* __restrict__ cepart) {
  __shared__ unsigned short lsA[128 * 32];
  __shared__ unsigned short lsB[128 * 32];
  int id = blockIdx.x;
  if (id < 256) {            // ce partials = X X^T, split-K x4: x 0..3, y 0..3, z 0..15
    gemm_core<EPI_F32, true>(xcn, N_, (size_t)C_ * N_, xcn, N_, (size_t)C_ * N_,
                             cepart, 512, (size_t)512 * 512 * 4, 1024, nullptr,
                             id & 3, (id >> 2) & 3, id >> 4, lsA, lsB);
  } else if (id < 384) {     // qkT = xnc @ wqk^T: x 0..31, y 0, z 0..3
    int t = id - 256;
    gemm_core<EPI_BF16, false>(xnc, 512, (size_t)N_ * C_, wqkb, 512, 0,
                               qkT, 128, (size_t)N_ * 128 * 2, 512, nullptr,
                               t & 31, 0, t >> 5, lsA, lsB);
  } else {                   // v = wv @ x: x 0..3, y 0..31, z 0..3
    int t = id - 384;
    gemm_core<EPI_BF16, false>(wvb, 512, 0, xnc, 512, (size_t)N_ * C_,
                               vmat, N_, (size_t)C_ * N_ * 2, 512, nullptr,
                               t & 3, (t >> 2) & 31, t >> 7, lsA, lsB);
  }
}

// ---------------- fused position attention (r5 base + E 4m x 2n split) ----------------
#define QR 128
#define CC 256
#define KT 128

__global__ __launch_bounds__(512, 2)
void fused_pa_k(const unsigned short* __restrict__ qkT,   // [B][N][128] (q|k)
                const unsigned short* __restrict__ vmat,  // [B][C][N]
                const unsigned short* __restrict__ caT,   // [B][N][C]
                const unsigned short* __restrict__ xnc,   // [B][N][C]
                const float* __restrict__ gpa_p, const float* __restrict__ gca_p,
                unsigned short* __restrict__ sT) {        // [B][N][C]
  __shared__ unsigned short lsQ[QR * 64];
  __shared__ unsigned short lsK[2][KT * 64];
  __shared__ unsigned short lsV[CC * KT];
  __shared__ unsigned short lsP[QR * KT];
  __shared__ float lsL[8][64];
  __shared__ float invL[QR];

  const int bid = blockIdx.x;
  const int combo = bid & 7;                 // b*2+chalf -> same XCD shares V-half
  const int b = combo >> 1, chalf = combo & 1;
  const int qt = bid >> 3;
  const int n0 = qt * QR, c0 = chalf * CC;

  const int tid = threadIdx.x, lane = tid & 63, w = tid >> 6;
  const int fr = lane & 15, fq = lane >> 4;  // fragment row / k-quarter
  const int wr = w >> 2, wc = w & 3;         // PV wave out-tile 64x64
  const int ms = (w & 3) * 32;               // E-phase m-slice (32 rows)
  const int nb = (w >> 2) * 64;              // E-phase n-half (64 cols)

  const unsigned short* qk_b = qkT + (size_t)b * N_ * 128;
  const unsigned short* v_b  = vmat + (size_t)b * C_ * N_;

  f32x4 acc[4][4];
#pragma unroll
  for (int i = 0; i < 4; ++i)
#pragma unroll
    for (int j = 0; j < 4; ++j) acc[i][j] = (f32x4){0.f, 0.f, 0.f, 0.f};
  float lsum[4] = {0.f, 0.f, 0.f, 0.f};

  // stage Q (once) and K[0]
#pragma unroll
  for (int j = 0; j < 2; ++j) {
    int idx = j * 512 + tid;
    int r = idx >> 3, g = idx & 7;
    async16(qk_b + (size_t)(n0 + r) * 128 + ((g ^ (r & 7)) << 3), (char*)lsQ + idx * 16);
  }
#pragma unroll
  for (int j = 0; j < 2; ++j) {
    int idx = j * 512 + tid;
    int r = idx >> 3, g = idx & 7;
    async16(qk_b + (size_t)r * 128 + 64 + ((g ^ (r & 7)) << 3), (char*)lsK[0] + idx * 16);
  }
  __syncthreads();

  for (int it = 0; it < N_ / KT; ++it) {
    const int m0 = it * KT;
    // stage V[it]
#pragma unroll
    for (int j = 0; j < 8; ++j) {
      int idx = j * 512 + tid;
      int c = idx >> 4, g = idx & 15;
      async16(v_b + (size_t)(c0 + c) * N_ + m0 + ((g ^ (c & 7)) << 3), (char*)lsV + idx * 16);
    }
    // stage K[it+1]
    if (it < N_ / KT - 1) {
      unsigned short* dst = lsK[(it + 1) & 1];
#pragma unroll
      for (int j = 0; j < 2; ++j) {
        int idx = j * 512 + tid;
        int r = idx >> 3, g = idx & 7;
        async16(qk_b + (size_t)(m0 + KT + r) * 128 + 64 + ((g ^ (r & 7)) << 3),
                (char*)dst + idx * 16);
      }
    }
    // E^T = K . Q^T over k=64; wave owns 32m x 64n
    const unsigned short* lk = lsK[it & 1];
    short8 afk[2][2];
#pragma unroll
    for (int mi = 0; mi < 2; ++mi)
#pragma unroll
      for (int kk = 0; kk < 2; ++kk)
        afk[mi][kk] = *(const short8*)&lk[(ms + mi * 16 + fr) * 64 + (((kk * 4 + fq) ^ (fr & 7)) << 3)];
#pragma unroll
    for (int f = 0; f < 4; ++f) {
      int n = nb + f * 16 + fr;                // P row
      short8 bq0 = *(const short8*)&lsQ[n * 64 + (((0 * 4 + fq) ^ (fr & 7)) << 3)];
      short8 bq1 = *(const short8*)&lsQ[n * 64 + (((1 * 4 + fq) ^ (fr & 7)) << 3)];
      float part = 0.f;
#pragma unroll
      for (int mi = 0; mi < 2; ++mi) {
        f32x4 e = (f32x4){0.f, 0.f, 0.f, 0.f};
        e = __builtin_amdgcn_mfma_f32_16x16x32_bf16(afk[mi][0], bq0, e, 0, 0, 0);
        e = __builtin_amdgcn_mfma_f32_16x16x32_bf16(afk[mi][1], bq1, e, 0, 0, 0);
        float p0 = __expf(e[0]), p1 = __expf(e[1]), p2 = __expf(e[2]), p3 = __expf(e[3]);
        part += (p0 + p1) + (p2 + p3);
        int mb = ms + mi * 16 + fq * 4;        // 4 consecutive m
        us4_t pk = { f2b(p0), f2b(p1), f2b(p2), f2b(p3) };
        *(us4_t*)((char*)lsP + n * 256 + ((((mb >> 3) ^ (n & 7)) << 3) + (mb & 7)) * 2) = pk;
      }
      part += __shfl_xor(part, 16, 64);
      part += __shfl_xor(part, 32, 64);
      lsum[f] += part;
    }
    __syncthreads();   // P visible; V (and next K) landed
    // PV: out[n][c] += P[n][m] * V[c][m]
#pragma unroll
    for (int kk4 = 0; kk4 < 4; ++kk4) {
      short8 pa[4], vbf[4];
#pragma unroll
      for (int mi = 0; mi < 4; ++mi) {
        int n = wr * 64 + mi * 16 + fr;
        pa[mi] = *(const short8*)((const char*)lsP + n * 256 + (((kk4 * 4 + fq) ^ (n & 7)) << 4));
      }
#pragma unroll
      for (int ni = 0; ni < 4; ++ni) {
        int c = wc * 64 + ni * 16 + fr;
        vbf[ni] = *(const short8*)((const char*)lsV + c * 256 + (((kk4 * 4 + fq) ^ (c & 7)) << 4));
      }
#pragma unroll
      for (int mi = 0; mi < 4; ++mi)
#pragma unroll
        for (int ni = 0; ni < 4; ++ni)
          acc[mi][ni] = __builtin_amdgcn_mfma_f32_16x16x32_bf16(pa[mi], vbf[ni], acc[mi][ni], 0, 0, 0);
    }
    __syncthreads();   // all reads of lsP/lsV done before next stage/overwrite
  }

  // reduce rowsums: row n = nh*64 + j summed over 4 m-slice waves (w = nh*4 + ma)
  if (lane < 16) {
#pragma unroll
    for (int f = 0; f < 4; ++f) lsL[w][f * 16 + lane] = lsum[f];
  }
  __syncthreads();
  if (tid < QR) {
    int nh = tid >> 6, j = tid & 63;
    invL[tid] = 1.f / (lsL[4 * nh][j] + lsL[4 * nh + 1][j] + lsL[4 * nh + 2][j] + lsL[4 * nh + 3][j]);
  }
  __syncthreads();

  const float gpa = gpa_p[0], gca = gca_p[0];
#pragma unroll
  for (int mi = 0; mi < 4; ++mi)
#pragma unroll
    for (int ni = 0; ni < 4; ++ni)
#pragma unroll
      for (int r = 0; r < 4; ++r) {
        int nl = wr * 64 + mi * 16 + fq * 4 + r;
        int gn = n0 + nl;
        int gc = c0 + wc * 64 + ni * 16 + fr;
        size_t eo = ((size_t)b * N_ + gn) * C_ + gc;
        float sv = gpa * acc[mi][ni][r] * invL[nl] + gca * b2f(caT[eo]) + 2.f * b2f(xnc[eo]);
        sT[eo] = f2b(sv);
      }
}

// ---------------- channel-attention softmax over ce partials ----------------
__global__ __launch_bounds__(256) void ce_softmax_k(const float* __restrict__ cepart,
                                                    unsigned short* __restrict__ cattn) {
  int wid = threadIdx.x >> 6, lane = threadIdx.x & 63;
  size_t row = (size_t)blockIdx.x * 4 + wid;
  float v[8]; float mn = 3.4e38f;
#pragma unroll
  for (int i = 0; i < 8; ++i) {
    size_t idx = row * C_ + (size_t)(i * 64 + lane);
    float t = cepart[idx] + cepart[idx + 1048576] + cepart[idx + 2097152] + cepart[idx + 3145728];
    v[i] = t; mn = fminf(mn, t);
  }
#pragma unroll
  for (int o = 1; o < 64; o <<= 1) mn = fminf(mn, __shfl_xor(mn, o, 64));
  float s = 0.f, p[8];
#pragma unroll
  for (int i = 0; i < 8; ++i) { p[i] = expf(mn - v[i]); s += p[i]; }
#pragma unroll
  for (int o = 1; o < 64; o <<= 1) s += __shfl_xor(s, o, 64);
  float inv = 1.f / s;
  unsigned short* orow = cattn + row * C_;
#pragma unroll
  for (int i = 0; i < 8; ++i) orow[i * 64 + lane] = f2b(p[i] * inv);
}

// ---------------- BN finalize (inline, redundant per block) + apply + transpose + relu ----
__global__ __launch_bounds__(256) void bn_apply_k(const unsigned short* __restrict__ yT,
                                                  const float* __restrict__ part,
                                                  const float* __restrict__ bns,
                                                  const float* __restrict__ bnb,
                                                  float* __restrict__ out) {
  __shared__ float tile[64][65];
  __shared__ float red[4][64][2];
  __shared__ float abv[64][2];
  int n0 = blockIdx.x * 64, o0 = blockIdx.y * 64, b = blockIdx.z;
  int t = threadIdx.x;
  {
    int col = o0 + (t & 63), seg = t >> 6;
    float s = 0.f, q = 0.f;
    for (int p = seg * 32; p < seg * 32 + 32; ++p) {
      s += part[(size_t)p * 1024 + col * 2];
      q += part[(size_t)p * 1024 + col * 2 + 1];
    }
    red[seg][t & 63][0] = s; red[seg][t & 63][1] = q;
  }
  __syncthreads();
  if (t < 64) {
    float S = red[0][t][0] + red[1][t][0] + red[2][t][0] + red[3][t][0];
    float Q = red[0][t][1] + red[1][t][1] + red[2][t][1] + red[3][t][1];
    float mean = S * (1.f / 16384.f);
    float var  = Q * (1.f / 16384.f) - mean * mean;
    float istd = rsqrtf(var + BN_EPS);
    float a = bns[o0 + t] * istd;
    abv[t][0] = a;
    abv[t][1] = bnb[o0 + t] - mean * a;
  }
  __syncthreads();
  const unsigned short* yb = yT + ((size_t)b * N_ + n0) * C_ + o0;
#pragma unroll
  for (int j = 0; j < 16; ++j) {
    int lin = j * 256 + t;
    int rr = lin >> 6, cc = lin & 63;
    float v = b2f(yb[(size_t)rr * C_ + cc]);
    tile[cc][rr] = fmaxf(v * abv[cc][0] + abv[cc][1], 0.f);
  }
  __syncthreads();
  float* ob = out + ((size_t)b * C_ + o0) * N_ + n0;
#pragma unroll
  for (int j = 0; j < 16; ++j) {
    int lin = j * 256 + t;
    int rr = lin >> 6, cc = lin & 63;
    ob[(size_t)rr * N_ + cc] = tile[rr][cc];
  }
}

// ---------------- host launch ----------------

extern "C" void kernel_launch(void* const* d_in, const int* in_sizes, int n_in,
                              void* d_out, int out_size, void* d_ws, size_t ws_size,
                              hipStream_t stream) {
  (void)in_sizes; (void)n_in; (void)out_size; (void)ws_size;
  const float* x   = (const float*)d_in[0];
  const float* wq  = (const float*)d_in[1];
  const float* wk  = (const float*)d_in[2];
  const float* wv  = (const float*)d_in[3];
  const float* wf  = (const float*)d_in[4];
  const float* gpa = (const float*)d_in[5];
  const float* gca = (const float*)d_in[6];
  const float* bns = (const float*)d_in[7];
  const float* bnb = (const float*)d_in[8];
  float* out = (float*)d_out;

  char* ws = (char*)d_ws;
  size_t off = 0;
  auto carve = [&](size_t bytes) -> char* {
    off = (off + 255) & ~(size_t)255;
    char* p = ws + off; off += bytes; return p;
  };

  unsigned short* xcn   = (unsigned short*)carve((size_t)B_ * C_ * N_ * 2);  // reused as sT
  unsigned short* xnc   = (unsigned short*)carve((size_t)B_ * C_ * N_ * 2);
  unsigned short* wqkb  = (unsigned short*)carve(128 * 512 * 2);
  unsigned short* wvb   = (unsigned short*)carve(512 * 512 * 2);
  unsigned short* wfb   = (unsigned short*)carve(512 * 512 * 2);
  unsigned short* qkT   = (unsigned short*)carve((size_t)B_ * N_ * 128 * 2);
  unsigned short* vmat  = (unsigned short*)carve((size_t)B_ * C_ * N_ * 2);
  float*          cepart= (float*)carve((size_t)4 * B_ * 512 * 512 * 4);     // reused as yT (bf16)
  unsigned short* cattn = (unsigned short*)carve((size_t)B_ * 512 * 512 * 2);
  unsigned short* caT   = (unsigned short*)carve((size_t)B_ * N_ * C_ * 2);
  float*          bnpart= (float*)carve((size_t)128 * 1024 * 4);

  unsigned short* yT = (unsigned short*)cepart;  // overlay: cepart dead after ce_softmax
  unsigned short* sT = xcn;                      // overlay: xcn dead after ce GEMM

  // 1) conversions (x + weights in one launch)
  convert_x_k<<<dim3(C_ / 64, N_ / 64, 5), 256, 0, stream>>>(
      x, xcn, xnc, wq, wk, wv, wf, wqkb, wvb, wfb);

  // 2) merged independent GEMMs: ce (split-K, first), qkT, v — 896 blocks
  gemm3_k<<<dim3(896), 256, 0, stream>>>(xnc, xcn, wqkb, wvb, qkT, vmat, cepart);

  // 3) channel softmax -> cattn bf16
  ce_softmax_k<<<dim3(B_ * 512 / 4), 256, 0, stream>>>(cepart, cattn);

  // 4) caT[n][c] = xnc @ cattn^T
  gemm_bt<EPI_BF16><<<dim3(32, 4, 4), 256, 0, stream>>>(
      xnc, 512, (size_t)N_ * C_, cattn, 512, (size_t)512 * 512,
      caT, 512, (size_t)N_ * C_ * 2, 512, nullptr);

  // 5) fused position attention + combine epilogue -> sT
  fused_pa_k<<<dim3(256), 512, 0, stream>>>(qkT, vmat, caT, xnc, gpa, gca, sT);

  // 6) yT[n][o] = sT @ wfuse^T (bf16) with fused per-block BN column partials
  gemm_bt<EPI_YB><<<dim3(32, 4, 4), 256, 0, stream>>>(
      sT, 512, (size_t)N_ * C_, wfb, 512, 0,
      yT, 512, (size_t)N_ * C_ * 2, 512, bnpart);

  // 7) BN finalize (inline) + apply + transpose + relu
  bn_apply_k<<<dim3(N_ / 64, C_ / 64, B_), 256, 0, stream>>>(yT, bnpart, bns, bnb, out);
}